// Round 13
// baseline (548.907 us; speedup 1.0000x reference)
//
#include <hip/hip_runtime.h>
#include <hip/hip_bf16.h>

#define LRELU(v) ((v) > 0.0f ? (v) : 0.01f * (v))
#define EPS 0.1f

#define BIN_EPB 2048        // edges per k_bin block
#define BIN_CAP 12288       // bucket capacity (expected 8163, +45 sigma headroom)

// fast tanh via v_exp_f32 + v_rcp_f32: ~1e-7 abs err, saturates correctly
__device__ __forceinline__ float fast_tanh(float v)
{
    float e = __expf(2.0f * v);
    return 1.0f - 2.0f * __builtin_amdgcn_rcpf(e + 1.0f);
}

// bf16 <-> f32 (RNE pack); feature rows stored bf16 to halve gather traffic
__device__ __forceinline__ float bf2f(unsigned short h)
{
    return __uint_as_float(((unsigned int)h) << 16);
}
__device__ __forceinline__ unsigned short f2bf(float f)
{
    unsigned int u = __float_as_uint(f);
    u += 0x7FFFu + ((u >> 16) & 1u);
    return (unsigned short)(u >> 16);
}

// ---------------------------------------------------------------------------
// K0: transpose weights to [j][k] layout so each output's weights are
// contiguous -> s_load_dwordx4/x16 batches, ~64 weight-SGPRs live at a time.
// (Round-12 k_feat spilled ~100 MB scratch: the [k][j]-strided fully-unrolled
// second layer batched 256 weights into SGPRs -> SGPR 112 + VGPR spill.)
// ---------------------------------------------------------------------------
__global__ void k_prep(const float* __restrict__ W_num, const float* __restrict__ W_cat,
                       const float* __restrict__ W_tog,
                       float* __restrict__ WnT, float* __restrict__ WcT,
                       float* __restrict__ WtT)
{
    int t = threadIdx.x;            // one block, 256 threads
    for (int i = t; i < 32 * 20; i += 256) { int j = i / 20, k = i % 20; WnT[i] = W_num[k * 32 + j]; }
    for (int i = t; i < 32 * 12; i += 256) { int j = i / 12, k = i % 12; WcT[i] = W_cat[k * 32 + j]; }
    for (int i = t; i < 64 * 64; i += 256) { int j = i >> 6, k = i & 63;  WtT[i] = W_tog[k * 64 + j]; }
}

// ---------------------------------------------------------------------------
// K1: per-node feature MLP, thread-per-node, transposed weights.
// Second layer: dynamic j-loop (no unroll) with ILP-4 partial sums; mid[64]
// const-indexed -> VGPR-resident. Fuses al/ar dots. bf16 output row.
// ---------------------------------------------------------------------------
__global__ void __launch_bounds__(256, 2)
k_feat(const float* __restrict__ num_prop,
       const float* __restrict__ cat_prop,
       const float* __restrict__ WnT, const float* __restrict__ b_num,
       const float* __restrict__ WcT, const float* __restrict__ b_cat,
       const float* __restrict__ WtT, const float* __restrict__ b_tog,
       const float* __restrict__ att_l, const float* __restrict__ att_r,
       unsigned short* __restrict__ xb,
       float* __restrict__ al, float* __restrict__ ar, int N)
{
    int n = blockIdx.x * blockDim.x + threadIdx.x;
    if (n >= N) return;

    float num[20], cat[12];
    {
        const float* np_ = num_prop + (size_t)n * 20;
        #pragma unroll
        for (int k = 0; k < 20; k++) num[k] = np_[k];
        const float* cp = cat_prop + (size_t)n * 12;
        #pragma unroll
        for (int k = 0; k < 12; k++) cat[k] = cp[k];
    }

    float mid[64];
    #pragma unroll
    for (int j = 0; j < 32; j++) {
        const float* w = WnT + j * 20;
        float s0 = b_num[j], s1 = 0.0f;
        #pragma unroll
        for (int k = 0; k < 20; k += 2) {
            s0 = fmaf(num[k],     w[k],     s0);
            s1 = fmaf(num[k + 1], w[k + 1], s1);
        }
        float s = s0 + s1;
        mid[j] = LRELU(s);
    }
    #pragma unroll
    for (int j = 0; j < 32; j++) {
        const float* w = WcT + j * 12;
        float s0 = b_cat[j], s1 = 0.0f;
        #pragma unroll
        for (int k = 0; k < 12; k += 2) {
            s0 = fmaf(cat[k],     w[k],     s0);
            s1 = fmaf(cat[k + 1], w[k + 1], s1);
        }
        float s = s0 + s1;
        mid[32 + j] = LRELU(s);
    }

    float al_acc = 0.0f, ar_acc = 0.0f;
    unsigned short* xbrow = xb + (size_t)n * 64;
    #pragma unroll 1
    for (int j = 0; j < 64; j++) {           // dynamic uniform loop: small body,
        const float* w = WtT + j * 64;       // 64 contiguous weights -> s_load x16
        float s0 = b_tog[j], s1 = 0.0f, s2 = 0.0f, s3 = 0.0f;
        #pragma unroll
        for (int k = 0; k < 64; k += 4) {
            s0 = fmaf(mid[k],     w[k],     s0);
            s1 = fmaf(mid[k + 1], w[k + 1], s1);
            s2 = fmaf(mid[k + 2], w[k + 2], s2);
            s3 = fmaf(mid[k + 3], w[k + 3], s3);
        }
        float s = (s0 + s1) + (s2 + s3);
        s = LRELU(s);
        al_acc = fmaf(s, att_l[j], al_acc);
        ar_acc = fmaf(s, att_r[j], ar_acc);
        xbrow[j] = f2bf(s);
    }
    al[n] = al_acc;
    ar[n] = ar_acc;
}

// ---------------------------------------------------------------------------
// K2: radix partition phase 1 (no global atomics).
// ---------------------------------------------------------------------------
__global__ void k_bin(const int* __restrict__ src, const int* __restrict__ dst,
                      int* __restrict__ bucket_cnt,
                      int2* __restrict__ buckets, int E, int NB)
{
    __shared__ int  hist[256];
    __shared__ int  lbase[256];
    __shared__ int  gbase[256];
    __shared__ int2 stage[BIN_EPB];

    int tid  = threadIdx.x;          // blockDim = 256
    int base = blockIdx.x * BIN_EPB;

    hist[tid] = 0;
    __syncthreads();

    int s[8], d[8], rk[8];
    #pragma unroll
    for (int k = 0; k < 8; k++) {
        int e = base + k * 256 + tid;
        s[k] = -1;
        if (e < E) {
            s[k] = src[e];
            d[k] = dst[e];
            rk[k] = atomicAdd(&hist[d[k] >> 10], 1);
        }
    }
    __syncthreads();

    int v = hist[tid];
    lbase[tid] = v;
    __syncthreads();
    for (int off = 1; off < 256; off <<= 1) {
        int t = (tid >= off) ? lbase[tid - off] : 0;
        __syncthreads();
        lbase[tid] += t;
        __syncthreads();
    }
    int incl = lbase[tid];
    __syncthreads();
    lbase[tid] = incl - v;
    if (tid < NB && v > 0) gbase[tid] = atomicAdd(&bucket_cnt[tid], v);
    __syncthreads();

    #pragma unroll
    for (int k = 0; k < 8; k++) {
        if (s[k] >= 0) {
            int b = d[k] >> 10;
            stage[lbase[b] + rk[k]] = make_int2(s[k], d[k]);
        }
    }
    __syncthreads();

    int tot = min(BIN_EPB, E - base);
    for (int i = tid; i < tot; i += 256) {
        int2 p = stage[i];
        int b = p.y >> 10;
        buckets[(size_t)b * BIN_CAP + gbase[b] + (i - lbase[b])] = p;
    }
}

// ---------------------------------------------------------------------------
// K2b: per-bucket degree histogram (LDS counters, coalesced deg write).
// ---------------------------------------------------------------------------
__global__ void k_degB(const int2* __restrict__ buckets, const int* __restrict__ bucket_cnt,
                       int* __restrict__ deg, int N)
{
    __shared__ int cur[1024];
    int b   = blockIdx.x;
    int tid = threadIdx.x;          // blockDim = 1024
    cur[tid] = 0;
    __syncthreads();

    int cnt = bucket_cnt[b];
    const int2* bp = buckets + (size_t)b * BIN_CAP;
    for (int i = tid; i < cnt; i += 1024)
        atomicAdd(&cur[bp[i].y & 1023], 1);
    __syncthreads();

    int n = b * 1024 + tid;
    if (n < N) deg[n] = cur[tid];
}

// ---------------------------------------------------------------------------
// CSR scan over PADDED row lengths ((deg+7)&~7).
// ---------------------------------------------------------------------------
__global__ void k_scan1(const int* __restrict__ deg, int* __restrict__ row_start,
                        int* __restrict__ blockSums, int N)
{
    __shared__ int sh[1024];
    int tid = threadIdx.x;
    int i = blockIdx.x * 1024 + tid;
    int v = (i < N) ? ((deg[i] + 7) & ~7) : 0;      // padded length
    sh[tid] = v;
    __syncthreads();
    #pragma unroll
    for (int off = 1; off < 1024; off <<= 1) {
        int t = (tid >= off) ? sh[tid - off] : 0;
        __syncthreads();
        sh[tid] += t;
        __syncthreads();
    }
    if (i < N) row_start[i] = sh[tid] - v;          // exclusive within block
    if (tid == 1023) blockSums[blockIdx.x] = sh[1023];
}

__global__ void k_scan2(int* __restrict__ blockSums, int nb)
{
    __shared__ int sh[256];
    int tid = threadIdx.x;
    int v = (tid < nb) ? blockSums[tid] : 0;
    sh[tid] = v;
    __syncthreads();
    #pragma unroll
    for (int off = 1; off < 256; off <<= 1) {
        int t = (tid >= off) ? sh[tid - off] : 0;
        __syncthreads();
        sh[tid] += t;
        __syncthreads();
    }
    if (tid < nb) blockSums[tid] = sh[tid] - v;     // exclusive
}

// row_start += block offset; pack ald1 = {al, rsqrt(deg+1)}
__global__ void k_scan3(int* __restrict__ row_start, const int* __restrict__ blockSums,
                        const int* __restrict__ deg,
                        const float* __restrict__ al, float2* __restrict__ ald1, int N)
{
    int i = blockIdx.x * blockDim.x + threadIdx.x;
    if (i >= N) return;
    row_start[i] += blockSums[i >> 10];
    float dv = 1.0f / sqrtf((float)deg[i] + 1.0f);   // +1 self-loop
    ald1[i]  = make_float2(al[i], dv);
}

// ---------------------------------------------------------------------------
// K4: radix partition phase 2: bucket-local CSR fill (LDS cursors) + fused
// layer-1 alpha. Padding alphas slots are pre-memset to 0.
// ---------------------------------------------------------------------------
__global__ void k_fill2(const int2* __restrict__ buckets, const int* __restrict__ bucket_cnt,
                        const int* __restrict__ row_start,
                        const float2* __restrict__ ald, const float* __restrict__ arr,
                        int* __restrict__ srcs, int* __restrict__ dsts,
                        float* __restrict__ alphas)
{
    __shared__ int cur[1024];
    int b   = blockIdx.x;
    int tid = threadIdx.x;          // blockDim = 1024
    cur[tid] = 0;
    __syncthreads();

    int cnt = bucket_cnt[b];
    const int2* bp = buckets + (size_t)b * BIN_CAP;
    for (int i = tid; i < cnt; i += 1024) {
        int2 p = bp[i];
        int r = p.y & 1023;
        int o = atomicAdd(&cur[r], 1);
        int pos = row_start[p.y] + o;
        float2 as = ald[p.x];           // random 8B (L2/L3)
        float2 ad = ald[p.y];           // bucket-local
        srcs[pos]   = p.x;
        dsts[pos]   = p.y;
        alphas[pos] = fast_tanh(as.x + arr[p.y]) * as.y * ad.y;
    }
}

// ---------------------------------------------------------------------------
// K4b: edge-parallel alpha in CSR order (layer 2 only).
// ---------------------------------------------------------------------------
__global__ void k_alphaE(const int* __restrict__ srcs, const int* __restrict__ dsts,
                         const float2* __restrict__ ald, const float* __restrict__ arr,
                         float* __restrict__ alphas, int P)
{
    int p = blockIdx.x * blockDim.x + threadIdx.x;
    if (p >= P) return;
    int s = srcs[p];
    float a = 0.0f;
    if (s >= 0) {
        int d = dsts[p];
        float2 as = ald[s];
        float2 ad = ald[d];
        a = fast_tanh(as.x + arr[d]) * as.y * ad.y;
    }
    alphas[p] = a;
}

// ---------------------------------------------------------------------------
// K5: gather layer 1: wave-uniform n (readfirstlane) -> srcs/alphas on the
// scalar pipe, per-edge VALU = load+cvt+fma. Rows padded to x8. Fused
// finalize + al2/ar2 reductions; epilogue packs ald2 = {al2, dinv}.
// ---------------------------------------------------------------------------
__global__ void k_gather1(const int* __restrict__ srcs, const float* __restrict__ alphas,
                          const int* __restrict__ row_start, const int* __restrict__ deg,
                          const unsigned short* __restrict__ xb,
                          const float2* __restrict__ ald1, const float* __restrict__ ar,
                          const float* __restrict__ att_l, const float* __restrict__ att_r,
                          unsigned short* __restrict__ h1b, float2* __restrict__ ald2,
                          float* __restrict__ ar2, int N)
{
    int lane = threadIdx.x & 63;
    int n    = __builtin_amdgcn_readfirstlane(blockIdx.x * 4 + (threadIdx.x >> 6));
    if (n >= N) return;

    int    s0   = row_start[n];
    int    cnt  = deg[n];
    int    cntp = (cnt + 7) & ~7;
    float2 self = ald1[n];          // {al[n], dinv[n]}
    float  di   = self.y;
    float  arn  = ar[n];

    float acc = 0.0f;
    for (int j = 0; j < cntp; j += 8) {
        int sv[8]; float av[8], vv[8];
        #pragma unroll
        for (int t = 0; t < 8; t++) {
            sv[t] = max(srcs[s0 + j + t], 0);     // scalar: padding -> row 0
            av[t] = alphas[s0 + j + t];           // scalar: padding -> 0
        }
        #pragma unroll
        for (int t = 0; t < 8; t++) vv[t] = bf2f(xb[(size_t)sv[t] * 64 + lane]);
        #pragma unroll
        for (int t = 0; t < 8; t++) acc = fmaf(vv[t], av[t], acc);
    }

    float selfa = fast_tanh(self.x + arn) * di * di;
    float xnl   = bf2f(xb[(size_t)n * 64 + lane]);
    float v     = acc + (selfa + EPS) * xnl;

    float pl = v * att_l[lane];
    float pr = v * att_r[lane];
    #pragma unroll
    for (int off = 32; off > 0; off >>= 1) {
        pl += __shfl_down(pl, off);
        pr += __shfl_down(pr, off);
    }
    h1b[(size_t)n * 64 + lane] = f2bf(v);
    if (lane == 0) { ald2[n] = make_float2(pl, di); ar2[n] = pr; }
}

// ---------------------------------------------------------------------------
// K6: gather layer 2, same structure, fused finalize + abs-smooth.
// ---------------------------------------------------------------------------
__global__ void k_gather2(const int* __restrict__ srcs, const float* __restrict__ alphas,
                          const int* __restrict__ row_start, const int* __restrict__ deg,
                          const unsigned short* __restrict__ h1b,
                          const unsigned short* __restrict__ xb,
                          const float2* __restrict__ ald2, const float* __restrict__ ar2,
                          float* __restrict__ x2, int N)
{
    int lane = threadIdx.x & 63;
    int n    = __builtin_amdgcn_readfirstlane(blockIdx.x * 4 + (threadIdx.x >> 6));
    if (n >= N) return;

    int    s0   = row_start[n];
    int    cnt  = deg[n];
    int    cntp = (cnt + 7) & ~7;
    float2 self = ald2[n];          // {al2[n], dinv[n]}
    float  di   = self.y;
    float  arn  = ar2[n];

    float acc = 0.0f;
    for (int j = 0; j < cntp; j += 8) {
        int sv[8]; float av[8], vv[8];
        #pragma unroll
        for (int t = 0; t < 8; t++) {
            sv[t] = max(srcs[s0 + j + t], 0);
            av[t] = alphas[s0 + j + t];
        }
        #pragma unroll
        for (int t = 0; t < 8; t++) vv[t] = bf2f(h1b[(size_t)sv[t] * 64 + lane]);
        #pragma unroll
        for (int t = 0; t < 8; t++) acc = fmaf(vv[t], av[t], acc);
    }

    float selfa = fast_tanh(self.x + arn) * di * di;
    float h1l   = bf2f(h1b[(size_t)n * 64 + lane]);
    float xnl   = bf2f(xb[(size_t)n * 64 + lane]);
    float v = acc + selfa * h1l + EPS * xnl;
    x2[(size_t)n * 64 + lane] = sqrtf(v * v + 1e-8f);
}

// ---------------------------------------------------------------------------
// K7: per-user CSR segment sum
// ---------------------------------------------------------------------------
__global__ void k_usersum(const float* __restrict__ x2, const int* __restrict__ offs,
                          float* __restrict__ x3, int U)
{
    int u    = blockIdx.x;
    int lane = threadIdx.x;
    if (u >= U) return;
    int s = offs[u], e = offs[u + 1];
    float acc = 0.0f;
    for (int n = s; n < e; n++) acc += x2[(size_t)n * 64 + lane];
    x3[(size_t)u * 64 + lane] = acc;
}

// ---------------------------------------------------------------------------
// K8: head
// ---------------------------------------------------------------------------
__global__ void k_head(const float* __restrict__ x3, const int* __restrict__ re_index,
                       const float* __restrict__ W_f1, const float* __restrict__ b_f1,
                       const float* __restrict__ W_lab, const float* __restrict__ b_lab,
                       float* __restrict__ out, int U)
{
    int u = blockIdx.x * blockDim.x + threadIdx.x;
    if (u >= U) return;
    int r = re_index[u];
    const float* y = x3 + (size_t)r * 64;
    float yv[64];
    #pragma unroll
    for (int k = 0; k < 64; k++) yv[k] = y[k];
    float o0 = b_lab[0], o1 = b_lab[1];
    for (int j = 0; j < 32; j++) {
        float s = b_f1[j];
        #pragma unroll 8
        for (int k = 0; k < 64; k++) s = fmaf(yv[k], W_f1[k * 32 + j], s);
        s = LRELU(s);
        o0 = fmaf(s, W_lab[j * 2 + 0], o0);
        o1 = fmaf(s, W_lab[j * 2 + 1], o1);
    }
    out[(size_t)u * 2 + 0] = o0;
    out[(size_t)u * 2 + 1] = o1;
}

// ---------------------------------------------------------------------------
extern "C" void kernel_launch(void* const* d_in, const int* in_sizes, int n_in,
                              void* d_out, int out_size, void* d_ws, size_t ws_size,
                              hipStream_t stream)
{
    const float* num_prop = (const float*)d_in[0];
    const float* cat_prop = (const float*)d_in[1];
    const int*   offs     = (const int*)d_in[2];
    const int*   edge     = (const int*)d_in[3];
    const int*   re_index = (const int*)d_in[4];
    const float* W_num    = (const float*)d_in[5];
    const float* b_num    = (const float*)d_in[6];
    const float* W_cat    = (const float*)d_in[7];
    const float* b_cat    = (const float*)d_in[8];
    const float* W_tog    = (const float*)d_in[9];
    const float* b_tog    = (const float*)d_in[10];
    const float* att_l    = (const float*)d_in[11];
    const float* att_r    = (const float*)d_in[12];
    const float* W_f1     = (const float*)d_in[13];
    const float* b_f1     = (const float*)d_in[14];
    const float* W_lab    = (const float*)d_in[15];
    const float* b_lab    = (const float*)d_in[16];

    const int N = in_sizes[0] / 20;
    const int E = in_sizes[3] / 2;
    const int U = in_sizes[4];

    const int* src = edge;       // edge_index[0]
    const int* dst = edge + E;   // edge_index[1]

    const int    NB      = (N + 1023) >> 10;                   // dst buckets
    const size_t srcsCap = (size_t)E + 7ull * (size_t)N + 64;  // padded CSR capacity

    // workspace carve-up (4-byte units; int2/float2/ushort4 8B-aligned by layout)
    float* ws = (float*)d_ws;
    size_t off = 0;
    unsigned short* xb  = (unsigned short*)(ws + off); off += (size_t)N * 32;  // bf16 x
    unsigned short* h1b = (unsigned short*)(ws + off); off += (size_t)N * 32;  // bf16 h1
    float*  B    = ws + off; off += (size_t)N * 64;   // x2 (fp32)
    float2* ald1 = (float2*)(ws + off); off += (size_t)N * 2;
    float2* ald2 = (float2*)(ws + off); off += (size_t)N * 2;
    int2*   buckets = (int2*)(ws + off); off += (size_t)NB * BIN_CAP * 2;
    float*  al   = ws + off; off += N;
    float*  ar   = ws + off; off += N;
    float*  ar2  = ws + off; off += N;
    float*  x3   = ws + off; off += (size_t)U * 64;
    float*  WnT  = ws + off; off += 32 * 20;
    float*  WcT  = ws + off; off += 32 * 12;
    float*  WtT  = ws + off; off += 64 * 64;
    int*    deg        = (int*)(ws + off); off += N;
    int*    row_start  = (int*)(ws + off); off += N;
    int*    bucket_cnt = (int*)(ws + off); off += NB;
    int*    srcs       = (int*)(ws + off); off += srcsCap;
    int*    dsts       = (int*)(ws + off); off += srcsCap;
    float*  alphas     = (float*)(ws + off); off += srcsCap;
    int*    blockSums  = (int*)(ws + off); off += 256;

    hipMemsetAsync(bucket_cnt, 0, (size_t)NB * 4, stream);
    hipMemsetAsync(srcs, 0xFF, srcsCap * 4, stream);   // padding slots = -1
    hipMemsetAsync(alphas, 0, srcsCap * 4, stream);    // padding alphas = 0

    const int nbN4   = (N + 3) / 4;          // wave-per-node kernels, 4 nodes/block
    const int nbScan = (N + 1023) / 1024;    // <= 256 required by k_scan2
    const int nbBin  = (E + BIN_EPB - 1) / BIN_EPB;
    const int nbCap  = (int)((srcsCap + 255) / 256);

    // transpose weights (tiny, once per call)
    k_prep<<<1, 256, 0, stream>>>(W_num, W_cat, W_tog, WnT, WcT, WtT);

    k_feat<<<(N + 255) / 256, 256, 0, stream>>>(num_prop, cat_prop, WnT, b_num,
                                                WcT, b_cat, WtT, b_tog,
                                                att_l, att_r, xb, al, ar, N);

    // radix partition phase 1 (no global atomics)
    k_bin<<<nbBin, 256, 0, stream>>>(src, dst, bucket_cnt, buckets, E, NB);

    // per-bucket degree histogram (LDS counters, coalesced deg write)
    k_degB<<<NB, 1024, 0, stream>>>(buckets, bucket_cnt, deg, N);

    // padded CSR offsets
    k_scan1<<<nbScan, 1024, 0, stream>>>(deg, row_start, blockSums, N);
    k_scan2<<<1, 256, 0, stream>>>(blockSums, nbScan);
    k_scan3<<<(N + 255) / 256, 256, 0, stream>>>(row_start, blockSums, deg, al, ald1, N);

    // radix partition phase 2: bucket-local CSR fill + fused layer-1 alpha
    k_fill2<<<NB, 1024, 0, stream>>>(buckets, bucket_cnt, row_start, ald1, ar,
                                     srcs, dsts, alphas);

    // ---- FAConv layer 1 (h = h0 = x): scalar-offload gather ----
    k_gather1<<<nbN4, 256, 0, stream>>>(srcs, alphas, row_start, deg, xb, ald1, ar,
                                        att_l, att_r, h1b, ald2, ar2, N);

    // ---- FAConv layer 2 (h = h1, h0 = x) ----
    k_alphaE<<<nbCap, 256, 0, stream>>>(srcs, dsts, ald2, ar2, alphas, (int)srcsCap);
    k_gather2<<<nbN4, 256, 0, stream>>>(srcs, alphas, row_start, deg, h1b, xb,
                                        ald2, ar2, B, N);

    // ---- per-user pooling + head ----
    k_usersum<<<U, 64, 0, stream>>>(B, offs, x3, U);
    k_head<<<(U + 255) / 256, 256, 0, stream>>>(x3, re_index, W_f1, b_f1, W_lab, b_lab,
                                                (float*)d_out, U);
}

// Round 14
// 536.415 us; speedup vs baseline: 1.0233x; 1.0233x over previous
//
#include <hip/hip_runtime.h>
#include <hip/hip_bf16.h>

#define LRELU(v) ((v) > 0.0f ? (v) : 0.01f * (v))
#define EPS 0.1f

#define BIN_EPB 2048        // edges per k_bin block
#define BIN_CAP 12288       // bucket capacity (expected 8163, +45 sigma headroom)

// fast tanh via v_exp_f32 + v_rcp_f32: ~1e-7 abs err, saturates correctly
__device__ __forceinline__ float fast_tanh(float v)
{
    float e = __expf(2.0f * v);
    return 1.0f - 2.0f * __builtin_amdgcn_rcpf(e + 1.0f);
}

// bf16 <-> f32 (RNE pack); feature rows stored bf16 to halve gather traffic
__device__ __forceinline__ float bf2f(unsigned short h)
{
    return __uint_as_float(((unsigned int)h) << 16);
}
__device__ __forceinline__ unsigned short f2bf(float f)
{
    unsigned int u = __float_as_uint(f);
    u += 0x7FFFu + ((u >> 16) & 1u);
    return (unsigned short)(u >> 16);
}

// broadcast lane k's value to all lanes via v_readlane (uniform k -> SGPR)
__device__ __forceinline__ float lane_bcast(float v, int k)
{
    return __uint_as_float(__builtin_amdgcn_readlane(__float_as_uint(v), k));
}

// ---------------------------------------------------------------------------
// K1: per-node feature MLP, WAVE-per-4-nodes. Lane l holds mid channel l;
// layer-2 output channel j = lane, mid[k] broadcast via v_readlane (SGPR
// operand of the fma). No per-thread arrays -> ~20 VGPRs, structurally
// spill-proof (rounds 9/12/13: every thread-per-node variant with mid[64]
// per thread spilled 50-130 MB of scratch regardless of launch_bounds).
// xb row store is lane-contiguous (one 128 B line per node).
// ---------------------------------------------------------------------------
__global__ void __launch_bounds__(256)
k_feat(const float* __restrict__ num_prop,
       const float* __restrict__ cat_prop,
       const float* __restrict__ W_num, const float* __restrict__ b_num,
       const float* __restrict__ W_cat, const float* __restrict__ b_cat,
       const float* __restrict__ W_tog, const float* __restrict__ b_tog,
       const float* __restrict__ att_l, const float* __restrict__ att_r,
       unsigned short* __restrict__ xb,
       float* __restrict__ al, float* __restrict__ ar, int N)
{
    int lane = threadIdx.x & 63;
    int base = (blockIdx.x * 4 + (threadIdx.x >> 6)) * 4;   // 4 nodes per wave
    if (base >= N) return;

    float attl = att_l[lane];
    float attr = att_r[lane];

    // ---- layer 1: lane l computes mid channel l for each of 4 nodes ----
    float m0, m1, m2, m3;
    #pragma unroll
    for (int i = 0; i < 4; i++) {
        int n = __builtin_amdgcn_readfirstlane(min(base + i, N - 1));
        float s;
        if (lane < 32) {
            const float* np_ = num_prop + (size_t)n * 20;   // uniform -> s_load
            s = b_num[lane];
            #pragma unroll
            for (int k = 0; k < 20; k++) s = fmaf(np_[k], W_num[k * 32 + lane], s);
        } else {
            int c = lane - 32;
            const float* cp = cat_prop + (size_t)n * 12;    // uniform -> s_load
            s = b_cat[c];
            #pragma unroll
            for (int k = 0; k < 12; k++) s = fmaf(cp[k], W_cat[k * 32 + c], s);
        }
        s = LRELU(s);
        if (i == 0) m0 = s; else if (i == 1) m1 = s; else if (i == 2) m2 = s; else m3 = s;
    }

    // ---- layer 2: j = lane; 4 independent fma chains; mid via readlane ----
    float o0 = b_tog[lane], o1 = o0, o2 = o0, o3 = o0;
    #pragma unroll 8
    for (int k = 0; k < 64; k++) {
        float w = W_tog[k * 64 + lane];       // per-lane coalesced, L1-hot
        o0 = fmaf(lane_bcast(m0, k), w, o0);
        o1 = fmaf(lane_bcast(m1, k), w, o1);
        o2 = fmaf(lane_bcast(m2, k), w, o2);
        o3 = fmaf(lane_bcast(m3, k), w, o3);
    }

    // ---- epilogue: lrelu, fused al/ar reductions, bf16 row store ----
    #pragma unroll
    for (int i = 0; i < 4; i++) {
        int n = base + i;
        float s = (i == 0) ? o0 : (i == 1) ? o1 : (i == 2) ? o2 : o3;
        s = LRELU(s);
        float pl = s * attl;
        float pr = s * attr;
        #pragma unroll
        for (int off = 32; off > 0; off >>= 1) {
            pl += __shfl_down(pl, off);
            pr += __shfl_down(pr, off);
        }
        if (n < N) {
            xb[(size_t)n * 64 + lane] = f2bf(s);
            if (lane == 0) { al[n] = pl; ar[n] = pr; }
        }
    }
}

// ---------------------------------------------------------------------------
// K2: radix partition phase 1 (no global atomics).
// ---------------------------------------------------------------------------
__global__ void k_bin(const int* __restrict__ src, const int* __restrict__ dst,
                      int* __restrict__ bucket_cnt,
                      int2* __restrict__ buckets, int E, int NB)
{
    __shared__ int  hist[256];
    __shared__ int  lbase[256];
    __shared__ int  gbase[256];
    __shared__ int2 stage[BIN_EPB];

    int tid  = threadIdx.x;          // blockDim = 256
    int base = blockIdx.x * BIN_EPB;

    hist[tid] = 0;
    __syncthreads();

    int s[8], d[8], rk[8];
    #pragma unroll
    for (int k = 0; k < 8; k++) {
        int e = base + k * 256 + tid;
        s[k] = -1;
        if (e < E) {
            s[k] = src[e];
            d[k] = dst[e];
            rk[k] = atomicAdd(&hist[d[k] >> 10], 1);
        }
    }
    __syncthreads();

    int v = hist[tid];
    lbase[tid] = v;
    __syncthreads();
    for (int off = 1; off < 256; off <<= 1) {
        int t = (tid >= off) ? lbase[tid - off] : 0;
        __syncthreads();
        lbase[tid] += t;
        __syncthreads();
    }
    int incl = lbase[tid];
    __syncthreads();
    lbase[tid] = incl - v;
    if (tid < NB && v > 0) gbase[tid] = atomicAdd(&bucket_cnt[tid], v);
    __syncthreads();

    #pragma unroll
    for (int k = 0; k < 8; k++) {
        if (s[k] >= 0) {
            int b = d[k] >> 10;
            stage[lbase[b] + rk[k]] = make_int2(s[k], d[k]);
        }
    }
    __syncthreads();

    int tot = min(BIN_EPB, E - base);
    for (int i = tid; i < tot; i += 256) {
        int2 p = stage[i];
        int b = p.y >> 10;
        buckets[(size_t)b * BIN_CAP + gbase[b] + (i - lbase[b])] = p;
    }
}

// ---------------------------------------------------------------------------
// K2b: per-bucket degree histogram (LDS counters, coalesced deg write).
// ---------------------------------------------------------------------------
__global__ void k_degB(const int2* __restrict__ buckets, const int* __restrict__ bucket_cnt,
                       int* __restrict__ deg, int N)
{
    __shared__ int cur[1024];
    int b   = blockIdx.x;
    int tid = threadIdx.x;          // blockDim = 1024
    cur[tid] = 0;
    __syncthreads();

    int cnt = bucket_cnt[b];
    const int2* bp = buckets + (size_t)b * BIN_CAP;
    for (int i = tid; i < cnt; i += 1024)
        atomicAdd(&cur[bp[i].y & 1023], 1);
    __syncthreads();

    int n = b * 1024 + tid;
    if (n < N) deg[n] = cur[tid];
}

// ---------------------------------------------------------------------------
// CSR scan over PADDED row lengths ((deg+7)&~7).
// ---------------------------------------------------------------------------
__global__ void k_scan1(const int* __restrict__ deg, int* __restrict__ row_start,
                        int* __restrict__ blockSums, int N)
{
    __shared__ int sh[1024];
    int tid = threadIdx.x;
    int i = blockIdx.x * 1024 + tid;
    int v = (i < N) ? ((deg[i] + 7) & ~7) : 0;      // padded length
    sh[tid] = v;
    __syncthreads();
    #pragma unroll
    for (int off = 1; off < 1024; off <<= 1) {
        int t = (tid >= off) ? sh[tid - off] : 0;
        __syncthreads();
        sh[tid] += t;
        __syncthreads();
    }
    if (i < N) row_start[i] = sh[tid] - v;          // exclusive within block
    if (tid == 1023) blockSums[blockIdx.x] = sh[1023];
}

__global__ void k_scan2(int* __restrict__ blockSums, int nb)
{
    __shared__ int sh[256];
    int tid = threadIdx.x;
    int v = (tid < nb) ? blockSums[tid] : 0;
    sh[tid] = v;
    __syncthreads();
    #pragma unroll
    for (int off = 1; off < 256; off <<= 1) {
        int t = (tid >= off) ? sh[tid - off] : 0;
        __syncthreads();
        sh[tid] += t;
        __syncthreads();
    }
    if (tid < nb) blockSums[tid] = sh[tid] - v;     // exclusive
}

// row_start += block offset; pack ald1 = {al, rsqrt(deg+1)}
__global__ void k_scan3(int* __restrict__ row_start, const int* __restrict__ blockSums,
                        const int* __restrict__ deg,
                        const float* __restrict__ al, float2* __restrict__ ald1, int N)
{
    int i = blockIdx.x * blockDim.x + threadIdx.x;
    if (i >= N) return;
    row_start[i] += blockSums[i >> 10];
    float dv = 1.0f / sqrtf((float)deg[i] + 1.0f);   // +1 self-loop
    ald1[i]  = make_float2(al[i], dv);
}

// ---------------------------------------------------------------------------
// K4: radix partition phase 2: bucket-local CSR fill (LDS cursors) + fused
// layer-1 alpha. Padding alphas slots are pre-memset to 0.
// ---------------------------------------------------------------------------
__global__ void k_fill2(const int2* __restrict__ buckets, const int* __restrict__ bucket_cnt,
                        const int* __restrict__ row_start,
                        const float2* __restrict__ ald, const float* __restrict__ arr,
                        int* __restrict__ srcs, int* __restrict__ dsts,
                        float* __restrict__ alphas)
{
    __shared__ int cur[1024];
    int b   = blockIdx.x;
    int tid = threadIdx.x;          // blockDim = 1024
    cur[tid] = 0;
    __syncthreads();

    int cnt = bucket_cnt[b];
    const int2* bp = buckets + (size_t)b * BIN_CAP;
    for (int i = tid; i < cnt; i += 1024) {
        int2 p = bp[i];
        int r = p.y & 1023;
        int o = atomicAdd(&cur[r], 1);
        int pos = row_start[p.y] + o;
        float2 as = ald[p.x];           // random 8B (L2/L3)
        float2 ad = ald[p.y];           // bucket-local
        srcs[pos]   = p.x;
        dsts[pos]   = p.y;
        alphas[pos] = fast_tanh(as.x + arr[p.y]) * as.y * ad.y;
    }
}

// ---------------------------------------------------------------------------
// K4b: edge-parallel alpha in CSR order (layer 2 only).
// ---------------------------------------------------------------------------
__global__ void k_alphaE(const int* __restrict__ srcs, const int* __restrict__ dsts,
                         const float2* __restrict__ ald, const float* __restrict__ arr,
                         float* __restrict__ alphas, int P)
{
    int p = blockIdx.x * blockDim.x + threadIdx.x;
    if (p >= P) return;
    int s = srcs[p];
    float a = 0.0f;
    if (s >= 0) {
        int d = dsts[p];
        float2 as = ald[s];
        float2 ad = ald[d];
        a = fast_tanh(as.x + arr[d]) * as.y * ad.y;
    }
    alphas[p] = a;
}

// ---------------------------------------------------------------------------
// K5: gather layer 1: wave-uniform n (readfirstlane) -> srcs/alphas on the
// scalar pipe, per-edge VALU = load+cvt+fma. Rows padded to x8. Fused
// finalize + al2/ar2 reductions; epilogue packs ald2 = {al2, dinv}.
// ---------------------------------------------------------------------------
__global__ void k_gather1(const int* __restrict__ srcs, const float* __restrict__ alphas,
                          const int* __restrict__ row_start, const int* __restrict__ deg,
                          const unsigned short* __restrict__ xb,
                          const float2* __restrict__ ald1, const float* __restrict__ ar,
                          const float* __restrict__ att_l, const float* __restrict__ att_r,
                          unsigned short* __restrict__ h1b, float2* __restrict__ ald2,
                          float* __restrict__ ar2, int N)
{
    int lane = threadIdx.x & 63;
    int n    = __builtin_amdgcn_readfirstlane(blockIdx.x * 4 + (threadIdx.x >> 6));
    if (n >= N) return;

    int    s0   = row_start[n];
    int    cnt  = deg[n];
    int    cntp = (cnt + 7) & ~7;
    float2 self = ald1[n];          // {al[n], dinv[n]}
    float  di   = self.y;
    float  arn  = ar[n];

    float acc = 0.0f;
    for (int j = 0; j < cntp; j += 8) {
        int sv[8]; float av[8], vv[8];
        #pragma unroll
        for (int t = 0; t < 8; t++) {
            sv[t] = max(srcs[s0 + j + t], 0);     // scalar: padding -> row 0
            av[t] = alphas[s0 + j + t];           // scalar: padding -> 0
        }
        #pragma unroll
        for (int t = 0; t < 8; t++) vv[t] = bf2f(xb[(size_t)sv[t] * 64 + lane]);
        #pragma unroll
        for (int t = 0; t < 8; t++) acc = fmaf(vv[t], av[t], acc);
    }

    float selfa = fast_tanh(self.x + arn) * di * di;
    float xnl   = bf2f(xb[(size_t)n * 64 + lane]);
    float v     = acc + (selfa + EPS) * xnl;

    float pl = v * att_l[lane];
    float pr = v * att_r[lane];
    #pragma unroll
    for (int off = 32; off > 0; off >>= 1) {
        pl += __shfl_down(pl, off);
        pr += __shfl_down(pr, off);
    }
    h1b[(size_t)n * 64 + lane] = f2bf(v);
    if (lane == 0) { ald2[n] = make_float2(pl, di); ar2[n] = pr; }
}

// ---------------------------------------------------------------------------
// K6: gather layer 2, same structure, fused finalize + abs-smooth.
// ---------------------------------------------------------------------------
__global__ void k_gather2(const int* __restrict__ srcs, const float* __restrict__ alphas,
                          const int* __restrict__ row_start, const int* __restrict__ deg,
                          const unsigned short* __restrict__ h1b,
                          const unsigned short* __restrict__ xb,
                          const float2* __restrict__ ald2, const float* __restrict__ ar2,
                          float* __restrict__ x2, int N)
{
    int lane = threadIdx.x & 63;
    int n    = __builtin_amdgcn_readfirstlane(blockIdx.x * 4 + (threadIdx.x >> 6));
    if (n >= N) return;

    int    s0   = row_start[n];
    int    cnt  = deg[n];
    int    cntp = (cnt + 7) & ~7;
    float2 self = ald2[n];          // {al2[n], dinv[n]}
    float  di   = self.y;
    float  arn  = ar2[n];

    float acc = 0.0f;
    for (int j = 0; j < cntp; j += 8) {
        int sv[8]; float av[8], vv[8];
        #pragma unroll
        for (int t = 0; t < 8; t++) {
            sv[t] = max(srcs[s0 + j + t], 0);
            av[t] = alphas[s0 + j + t];
        }
        #pragma unroll
        for (int t = 0; t < 8; t++) vv[t] = bf2f(h1b[(size_t)sv[t] * 64 + lane]);
        #pragma unroll
        for (int t = 0; t < 8; t++) acc = fmaf(vv[t], av[t], acc);
    }

    float selfa = fast_tanh(self.x + arn) * di * di;
    float h1l   = bf2f(h1b[(size_t)n * 64 + lane]);
    float xnl   = bf2f(xb[(size_t)n * 64 + lane]);
    float v = acc + selfa * h1l + EPS * xnl;
    x2[(size_t)n * 64 + lane] = sqrtf(v * v + 1e-8f);
}

// ---------------------------------------------------------------------------
// K7: per-user CSR segment sum
// ---------------------------------------------------------------------------
__global__ void k_usersum(const float* __restrict__ x2, const int* __restrict__ offs,
                          float* __restrict__ x3, int U)
{
    int u    = blockIdx.x;
    int lane = threadIdx.x;
    if (u >= U) return;
    int s = offs[u], e = offs[u + 1];
    float acc = 0.0f;
    for (int n = s; n < e; n++) acc += x2[(size_t)n * 64 + lane];
    x3[(size_t)u * 64 + lane] = acc;
}

// ---------------------------------------------------------------------------
// K8: head
// ---------------------------------------------------------------------------
__global__ void k_head(const float* __restrict__ x3, const int* __restrict__ re_index,
                       const float* __restrict__ W_f1, const float* __restrict__ b_f1,
                       const float* __restrict__ W_lab, const float* __restrict__ b_lab,
                       float* __restrict__ out, int U)
{
    int u = blockIdx.x * blockDim.x + threadIdx.x;
    if (u >= U) return;
    int r = re_index[u];
    const float* y = x3 + (size_t)r * 64;
    float yv[64];
    #pragma unroll
    for (int k = 0; k < 64; k++) yv[k] = y[k];
    float o0 = b_lab[0], o1 = b_lab[1];
    for (int j = 0; j < 32; j++) {
        float s = b_f1[j];
        #pragma unroll 8
        for (int k = 0; k < 64; k++) s = fmaf(yv[k], W_f1[k * 32 + j], s);
        s = LRELU(s);
        o0 = fmaf(s, W_lab[j * 2 + 0], o0);
        o1 = fmaf(s, W_lab[j * 2 + 1], o1);
    }
    out[(size_t)u * 2 + 0] = o0;
    out[(size_t)u * 2 + 1] = o1;
}

// ---------------------------------------------------------------------------
extern "C" void kernel_launch(void* const* d_in, const int* in_sizes, int n_in,
                              void* d_out, int out_size, void* d_ws, size_t ws_size,
                              hipStream_t stream)
{
    const float* num_prop = (const float*)d_in[0];
    const float* cat_prop = (const float*)d_in[1];
    const int*   offs     = (const int*)d_in[2];
    const int*   edge     = (const int*)d_in[3];
    const int*   re_index = (const int*)d_in[4];
    const float* W_num    = (const float*)d_in[5];
    const float* b_num    = (const float*)d_in[6];
    const float* W_cat    = (const float*)d_in[7];
    const float* b_cat    = (const float*)d_in[8];
    const float* W_tog    = (const float*)d_in[9];
    const float* b_tog    = (const float*)d_in[10];
    const float* att_l    = (const float*)d_in[11];
    const float* att_r    = (const float*)d_in[12];
    const float* W_f1     = (const float*)d_in[13];
    const float* b_f1     = (const float*)d_in[14];
    const float* W_lab    = (const float*)d_in[15];
    const float* b_lab    = (const float*)d_in[16];

    const int N = in_sizes[0] / 20;
    const int E = in_sizes[3] / 2;
    const int U = in_sizes[4];

    const int* src = edge;       // edge_index[0]
    const int* dst = edge + E;   // edge_index[1]

    const int    NB      = (N + 1023) >> 10;                   // dst buckets
    const size_t srcsCap = (size_t)E + 7ull * (size_t)N + 64;  // padded CSR capacity

    // workspace carve-up (4-byte units; int2/float2 8B-aligned by layout)
    float* ws = (float*)d_ws;
    size_t off = 0;
    unsigned short* xb  = (unsigned short*)(ws + off); off += (size_t)N * 32;  // bf16 x
    unsigned short* h1b = (unsigned short*)(ws + off); off += (size_t)N * 32;  // bf16 h1
    float*  B    = ws + off; off += (size_t)N * 64;   // x2 (fp32)
    float2* ald1 = (float2*)(ws + off); off += (size_t)N * 2;
    float2* ald2 = (float2*)(ws + off); off += (size_t)N * 2;
    int2*   buckets = (int2*)(ws + off); off += (size_t)NB * BIN_CAP * 2;
    float*  al   = ws + off; off += N;
    float*  ar   = ws + off; off += N;
    float*  ar2  = ws + off; off += N;
    float*  x3   = ws + off; off += (size_t)U * 64;
    int*    deg        = (int*)(ws + off); off += N;
    int*    row_start  = (int*)(ws + off); off += N;
    int*    bucket_cnt = (int*)(ws + off); off += NB;
    int*    srcs       = (int*)(ws + off); off += srcsCap;
    int*    dsts       = (int*)(ws + off); off += srcsCap;
    float*  alphas     = (float*)(ws + off); off += srcsCap;
    int*    blockSums  = (int*)(ws + off); off += 256;

    hipMemsetAsync(bucket_cnt, 0, (size_t)NB * 4, stream);
    hipMemsetAsync(srcs, 0xFF, srcsCap * 4, stream);   // padding slots = -1
    hipMemsetAsync(alphas, 0, srcsCap * 4, stream);    // padding alphas = 0

    const int nbN4   = (N + 3) / 4;          // wave-per-node kernels, 4 nodes/block
    const int nbScan = (N + 1023) / 1024;    // <= 256 required by k_scan2
    const int nbBin  = (E + BIN_EPB - 1) / BIN_EPB;
    const int nbCap  = (int)((srcsCap + 255) / 256);

    // wave-per-4-nodes MLP: block of 4 waves covers 16 nodes
    k_feat<<<(N + 15) / 16, 256, 0, stream>>>(num_prop, cat_prop, W_num, b_num,
                                              W_cat, b_cat, W_tog, b_tog,
                                              att_l, att_r, xb, al, ar, N);

    // radix partition phase 1 (no global atomics)
    k_bin<<<nbBin, 256, 0, stream>>>(src, dst, bucket_cnt, buckets, E, NB);

    // per-bucket degree histogram (LDS counters, coalesced deg write)
    k_degB<<<NB, 1024, 0, stream>>>(buckets, bucket_cnt, deg, N);

    // padded CSR offsets
    k_scan1<<<nbScan, 1024, 0, stream>>>(deg, row_start, blockSums, N);
    k_scan2<<<1, 256, 0, stream>>>(blockSums, nbScan);
    k_scan3<<<(N + 255) / 256, 256, 0, stream>>>(row_start, blockSums, deg, al, ald1, N);

    // radix partition phase 2: bucket-local CSR fill + fused layer-1 alpha
    k_fill2<<<NB, 1024, 0, stream>>>(buckets, bucket_cnt, row_start, ald1, ar,
                                     srcs, dsts, alphas);

    // ---- FAConv layer 1 (h = h0 = x): scalar-offload gather ----
    k_gather1<<<nbN4, 256, 0, stream>>>(srcs, alphas, row_start, deg, xb, ald1, ar,
                                        att_l, att_r, h1b, ald2, ar2, N);

    // ---- FAConv layer 2 (h = h1, h0 = x) ----
    k_alphaE<<<nbCap, 256, 0, stream>>>(srcs, dsts, ald2, ar2, alphas, (int)srcsCap);
    k_gather2<<<nbN4, 256, 0, stream>>>(srcs, alphas, row_start, deg, h1b, xb,
                                        ald2, ar2, B, N);

    // ---- per-user pooling + head ----
    k_usersum<<<U, 64, 0, stream>>>(B, offs, x3, U);
    k_head<<<(U + 255) / 256, 256, 0, stream>>>(x3, re_index, W_f1, b_f1, W_lab, b_lab,
                                                (float*)d_out, U);
}

// Round 15
// 520.122 us; speedup vs baseline: 1.0553x; 1.0313x over previous
//
#include <hip/hip_runtime.h>
#include <hip/hip_bf16.h>

#define LRELU(v) ((v) > 0.0f ? (v) : 0.01f * (v))
#define EPS 0.1f

#define BIN_EPB 2048        // edges per k_bin block
#define BIN_CAP 12288       // bucket capacity (expected 8163, +45 sigma headroom)

typedef __attribute__((ext_vector_type(8))) short bf16x8;
typedef __attribute__((ext_vector_type(4))) float f32x4;

// fast tanh via v_exp_f32 + v_rcp_f32: ~1e-7 abs err, saturates correctly
__device__ __forceinline__ float fast_tanh(float v)
{
    float e = __expf(2.0f * v);
    return 1.0f - 2.0f * __builtin_amdgcn_rcpf(e + 1.0f);
}

// bf16 <-> f32 (RNE pack); feature rows stored bf16 to halve gather traffic
__device__ __forceinline__ float bf2f(unsigned short h)
{
    return __uint_as_float(((unsigned int)h) << 16);
}
__device__ __forceinline__ unsigned short f2bf(float f)
{
    unsigned int u = __float_as_uint(f);
    u += 0x7FFFu + ((u >> 16) & 1u);
    return (unsigned short)(u >> 16);
}

// ---------------------------------------------------------------------------
// K0: pack W_tog into bf16 MFMA B-fragment order.
// Wb[(kt*4+nt)*512 + lane*8 + j] = bf16(W_tog[(kt*32+(lane>>4)*8+j)*64 + nt*16+(lane&15)])
// so a wave's B-frag for tile (kt,nt) is one 16B load per lane.
// ---------------------------------------------------------------------------
__global__ void k_prep(const float* __restrict__ W_tog, unsigned short* __restrict__ Wb)
{
    int t = threadIdx.x;            // one block, 256 threads
    for (int i = t; i < 8 * 512; i += 256) {
        int tile = i >> 9;          // 0..7 = kt*4+nt
        int kt   = tile >> 2, nt = tile & 3;
        int lane = (i >> 3) & 63;
        int j    = i & 7;
        int k    = kt * 32 + (lane >> 4) * 8 + j;
        int n    = nt * 16 + (lane & 15);
        Wb[i] = f2bf(W_tog[k * 64 + n]);
    }
}

// ---------------------------------------------------------------------------
// K1: per-node feature MLP, block = 64 nodes (4 waves x 16 nodes).
// Layer 1: lane = mid channel, per-node scalar input loads -> bf16 mid in LDS
// (row pitch 72 bf16 breaks the 128B bank stride).
// Layer 2: mfma_f32_16x16x32_bf16 — wave computes its 16-node x 64-out tile
// as 4 n-tiles x 2 k-steps. A-frag: lane l = mid[l&15][quad*8+j] (ds_read_b128).
// B-frag: prepacked Wb. C/D: col=lane&15, row=quad*4+reg (m89-verified layout).
// Epilogue fuses bias+lrelu, bf16 x store, al/ar quad reductions (shfl_xor).
// (Rounds 9/12/13: thread-per-node + mid[64] spilled regardless of bounds;
// round 14 readlane form was VALU-bound at 2 inst/(node,k) -> 100 us.)
// ---------------------------------------------------------------------------
__global__ void __launch_bounds__(256)
k_feat(const float* __restrict__ num_prop,
       const float* __restrict__ cat_prop,
       const float* __restrict__ W_num, const float* __restrict__ b_num,
       const float* __restrict__ W_cat, const float* __restrict__ b_cat,
       const unsigned short* __restrict__ Wb, const float* __restrict__ b_tog,
       const float* __restrict__ att_l, const float* __restrict__ att_r,
       unsigned short* __restrict__ xb,
       float* __restrict__ al, float* __restrict__ ar, int N)
{
    __shared__ unsigned short mid[64][72];   // bf16, +8 pad

    int lane = threadIdx.x & 63;
    int w    = threadIdx.x >> 6;             // wave 0..3
    int blockStart = blockIdx.x * 64;

    // ---- layer 1: wave w computes nodes w*16..w*16+15 (lane = channel) ----
    for (int i = 0; i < 16; i++) {
        int nl = w * 16 + i;
        int n  = __builtin_amdgcn_readfirstlane(min(blockStart + nl, N - 1));
        float s;
        if (lane < 32) {
            const float* np_ = num_prop + (size_t)n * 20;   // uniform -> s_load
            s = b_num[lane];
            #pragma unroll
            for (int k = 0; k < 20; k++) s = fmaf(np_[k], W_num[k * 32 + lane], s);
        } else {
            int c = lane - 32;
            const float* cp = cat_prop + (size_t)n * 12;    // uniform -> s_load
            s = b_cat[c];
            #pragma unroll
            for (int k = 0; k < 12; k++) s = fmaf(cp[k], W_cat[k * 32 + c], s);
        }
        s = LRELU(s);
        mid[nl][lane] = f2bf(s);
    }
    __syncthreads();

    // ---- layer 2: MFMA ----
    int q   = lane >> 4;                     // quad
    int c16 = lane & 15;

    bf16x8 a0 = *(const bf16x8*)&mid[w * 16 + c16][q * 8];        // k 0..31
    bf16x8 a1 = *(const bf16x8*)&mid[w * 16 + c16][32 + q * 8];   // k 32..63

    float pal[4] = {0, 0, 0, 0};
    float par[4] = {0, 0, 0, 0};

    #pragma unroll
    for (int nt = 0; nt < 4; nt++) {
        bf16x8 b0 = *(const bf16x8*)&Wb[(0 * 4 + nt) * 512 + lane * 8];
        bf16x8 b1 = *(const bf16x8*)&Wb[(1 * 4 + nt) * 512 + lane * 8];
        f32x4 acc = {0.0f, 0.0f, 0.0f, 0.0f};
        acc = __builtin_amdgcn_mfma_f32_16x16x32_bf16(a0, b0, acc, 0, 0, 0);
        acc = __builtin_amdgcn_mfma_f32_16x16x32_bf16(a1, b1, acc, 0, 0, 0);

        int   ch  = nt * 16 + c16;
        float bt  = b_tog[ch];
        float atl = att_l[ch];
        float atr = att_r[ch];
        #pragma unroll
        for (int r = 0; r < 4; r++) {
            float s = acc[r] + bt;
            s = LRELU(s);
            int n = blockStart + w * 16 + q * 4 + r;
            if (n < N) xb[(size_t)n * 64 + ch] = f2bf(s);
            pal[r] = fmaf(s, atl, pal[r]);
            par[r] = fmaf(s, atr, par[r]);
        }
    }

    // reduce al/ar across the 16 lanes of each quad (xor<16 stays in-quad)
    #pragma unroll
    for (int r = 0; r < 4; r++) {
        float pl = pal[r], pr = par[r];
        #pragma unroll
        for (int off = 8; off > 0; off >>= 1) {
            pl += __shfl_xor(pl, off);
            pr += __shfl_xor(pr, off);
        }
        int n = blockStart + w * 16 + q * 4 + r;
        if (c16 == 0 && n < N) { al[n] = pl; ar[n] = pr; }
    }
}

// ---------------------------------------------------------------------------
// K2: radix partition phase 1 (no global atomics).
// ---------------------------------------------------------------------------
__global__ void k_bin(const int* __restrict__ src, const int* __restrict__ dst,
                      int* __restrict__ bucket_cnt,
                      int2* __restrict__ buckets, int E, int NB)
{
    __shared__ int  hist[256];
    __shared__ int  lbase[256];
    __shared__ int  gbase[256];
    __shared__ int2 stage[BIN_EPB];

    int tid  = threadIdx.x;          // blockDim = 256
    int base = blockIdx.x * BIN_EPB;

    hist[tid] = 0;
    __syncthreads();

    int s[8], d[8], rk[8];
    #pragma unroll
    for (int k = 0; k < 8; k++) {
        int e = base + k * 256 + tid;
        s[k] = -1;
        if (e < E) {
            s[k] = src[e];
            d[k] = dst[e];
            rk[k] = atomicAdd(&hist[d[k] >> 10], 1);
        }
    }
    __syncthreads();

    int v = hist[tid];
    lbase[tid] = v;
    __syncthreads();
    for (int off = 1; off < 256; off <<= 1) {
        int t = (tid >= off) ? lbase[tid - off] : 0;
        __syncthreads();
        lbase[tid] += t;
        __syncthreads();
    }
    int incl = lbase[tid];
    __syncthreads();
    lbase[tid] = incl - v;
    if (tid < NB && v > 0) gbase[tid] = atomicAdd(&bucket_cnt[tid], v);
    __syncthreads();

    #pragma unroll
    for (int k = 0; k < 8; k++) {
        if (s[k] >= 0) {
            int b = d[k] >> 10;
            stage[lbase[b] + rk[k]] = make_int2(s[k], d[k]);
        }
    }
    __syncthreads();

    int tot = min(BIN_EPB, E - base);
    for (int i = tid; i < tot; i += 256) {
        int2 p = stage[i];
        int b = p.y >> 10;
        buckets[(size_t)b * BIN_CAP + gbase[b] + (i - lbase[b])] = p;
    }
}

// ---------------------------------------------------------------------------
// K2b: per-bucket degree histogram (LDS counters, coalesced deg write).
// ---------------------------------------------------------------------------
__global__ void k_degB(const int2* __restrict__ buckets, const int* __restrict__ bucket_cnt,
                       int* __restrict__ deg, int N)
{
    __shared__ int cur[1024];
    int b   = blockIdx.x;
    int tid = threadIdx.x;          // blockDim = 1024
    cur[tid] = 0;
    __syncthreads();

    int cnt = bucket_cnt[b];
    const int2* bp = buckets + (size_t)b * BIN_CAP;
    for (int i = tid; i < cnt; i += 1024)
        atomicAdd(&cur[bp[i].y & 1023], 1);
    __syncthreads();

    int n = b * 1024 + tid;
    if (n < N) deg[n] = cur[tid];
}

// ---------------------------------------------------------------------------
// CSR scan over PADDED row lengths ((deg+7)&~7).
// ---------------------------------------------------------------------------
__global__ void k_scan1(const int* __restrict__ deg, int* __restrict__ row_start,
                        int* __restrict__ blockSums, int N)
{
    __shared__ int sh[1024];
    int tid = threadIdx.x;
    int i = blockIdx.x * 1024 + tid;
    int v = (i < N) ? ((deg[i] + 7) & ~7) : 0;      // padded length
    sh[tid] = v;
    __syncthreads();
    #pragma unroll
    for (int off = 1; off < 1024; off <<= 1) {
        int t = (tid >= off) ? sh[tid - off] : 0;
        __syncthreads();
        sh[tid] += t;
        __syncthreads();
    }
    if (i < N) row_start[i] = sh[tid] - v;          // exclusive within block
    if (tid == 1023) blockSums[blockIdx.x] = sh[1023];
}

__global__ void k_scan2(int* __restrict__ blockSums, int nb)
{
    __shared__ int sh[256];
    int tid = threadIdx.x;
    int v = (tid < nb) ? blockSums[tid] : 0;
    sh[tid] = v;
    __syncthreads();
    #pragma unroll
    for (int off = 1; off < 256; off <<= 1) {
        int t = (tid >= off) ? sh[tid - off] : 0;
        __syncthreads();
        sh[tid] += t;
        __syncthreads();
    }
    if (tid < nb) blockSums[tid] = sh[tid] - v;     // exclusive
}

// row_start += block offset; pack ald1 = {al, rsqrt(deg+1)}
__global__ void k_scan3(int* __restrict__ row_start, const int* __restrict__ blockSums,
                        const int* __restrict__ deg,
                        const float* __restrict__ al, float2* __restrict__ ald1, int N)
{
    int i = blockIdx.x * blockDim.x + threadIdx.x;
    if (i >= N) return;
    row_start[i] += blockSums[i >> 10];
    float dv = 1.0f / sqrtf((float)deg[i] + 1.0f);   // +1 self-loop
    ald1[i]  = make_float2(al[i], dv);
}

// ---------------------------------------------------------------------------
// K4: radix partition phase 2: bucket-local CSR fill (LDS cursors) + fused
// layer-1 alpha. Padding alphas slots are pre-memset to 0.
// ---------------------------------------------------------------------------
__global__ void k_fill2(const int2* __restrict__ buckets, const int* __restrict__ bucket_cnt,
                        const int* __restrict__ row_start,
                        const float2* __restrict__ ald, const float* __restrict__ arr,
                        int* __restrict__ srcs, int* __restrict__ dsts,
                        float* __restrict__ alphas)
{
    __shared__ int cur[1024];
    int b   = blockIdx.x;
    int tid = threadIdx.x;          // blockDim = 1024
    cur[tid] = 0;
    __syncthreads();

    int cnt = bucket_cnt[b];
    const int2* bp = buckets + (size_t)b * BIN_CAP;
    for (int i = tid; i < cnt; i += 1024) {
        int2 p = bp[i];
        int r = p.y & 1023;
        int o = atomicAdd(&cur[r], 1);
        int pos = row_start[p.y] + o;
        float2 as = ald[p.x];           // random 8B (L2/L3)
        float2 ad = ald[p.y];           // bucket-local
        srcs[pos]   = p.x;
        dsts[pos]   = p.y;
        alphas[pos] = fast_tanh(as.x + arr[p.y]) * as.y * ad.y;
    }
}

// ---------------------------------------------------------------------------
// K4b: edge-parallel alpha in CSR order (layer 2 only).
// ---------------------------------------------------------------------------
__global__ void k_alphaE(const int* __restrict__ srcs, const int* __restrict__ dsts,
                         const float2* __restrict__ ald, const float* __restrict__ arr,
                         float* __restrict__ alphas, int P)
{
    int p = blockIdx.x * blockDim.x + threadIdx.x;
    if (p >= P) return;
    int s = srcs[p];
    float a = 0.0f;
    if (s >= 0) {
        int d = dsts[p];
        float2 as = ald[s];
        float2 ad = ald[d];
        a = fast_tanh(as.x + arr[d]) * as.y * ad.y;
    }
    alphas[p] = a;
}

// ---------------------------------------------------------------------------
// K5: gather layer 1: wave-uniform n (readfirstlane) -> srcs/alphas on the
// scalar pipe, per-edge VALU = load+cvt+fma. Rows padded to x8. Fused
// finalize + al2/ar2 reductions; epilogue packs ald2 = {al2, dinv}.
// ---------------------------------------------------------------------------
__global__ void k_gather1(const int* __restrict__ srcs, const float* __restrict__ alphas,
                          const int* __restrict__ row_start, const int* __restrict__ deg,
                          const unsigned short* __restrict__ xb,
                          const float2* __restrict__ ald1, const float* __restrict__ ar,
                          const float* __restrict__ att_l, const float* __restrict__ att_r,
                          unsigned short* __restrict__ h1b, float2* __restrict__ ald2,
                          float* __restrict__ ar2, int N)
{
    int lane = threadIdx.x & 63;
    int n    = __builtin_amdgcn_readfirstlane(blockIdx.x * 4 + (threadIdx.x >> 6));
    if (n >= N) return;

    int    s0   = row_start[n];
    int    cnt  = deg[n];
    int    cntp = (cnt + 7) & ~7;
    float2 self = ald1[n];          // {al[n], dinv[n]}
    float  di   = self.y;
    float  arn  = ar[n];

    float acc = 0.0f;
    for (int j = 0; j < cntp; j += 8) {
        int sv[8]; float av[8], vv[8];
        #pragma unroll
        for (int t = 0; t < 8; t++) {
            sv[t] = max(srcs[s0 + j + t], 0);     // scalar: padding -> row 0
            av[t] = alphas[s0 + j + t];           // scalar: padding -> 0
        }
        #pragma unroll
        for (int t = 0; t < 8; t++) vv[t] = bf2f(xb[(size_t)sv[t] * 64 + lane]);
        #pragma unroll
        for (int t = 0; t < 8; t++) acc = fmaf(vv[t], av[t], acc);
    }

    float selfa = fast_tanh(self.x + arn) * di * di;
    float xnl   = bf2f(xb[(size_t)n * 64 + lane]);
    float v     = acc + (selfa + EPS) * xnl;

    float pl = v * att_l[lane];
    float pr = v * att_r[lane];
    #pragma unroll
    for (int off = 32; off > 0; off >>= 1) {
        pl += __shfl_down(pl, off);
        pr += __shfl_down(pr, off);
    }
    h1b[(size_t)n * 64 + lane] = f2bf(v);
    if (lane == 0) { ald2[n] = make_float2(pl, di); ar2[n] = pr; }
}

// ---------------------------------------------------------------------------
// K6: gather layer 2, same structure, fused finalize + abs-smooth.
// ---------------------------------------------------------------------------
__global__ void k_gather2(const int* __restrict__ srcs, const float* __restrict__ alphas,
                          const int* __restrict__ row_start, const int* __restrict__ deg,
                          const unsigned short* __restrict__ h1b,
                          const unsigned short* __restrict__ xb,
                          const float2* __restrict__ ald2, const float* __restrict__ ar2,
                          float* __restrict__ x2, int N)
{
    int lane = threadIdx.x & 63;
    int n    = __builtin_amdgcn_readfirstlane(blockIdx.x * 4 + (threadIdx.x >> 6));
    if (n >= N) return;

    int    s0   = row_start[n];
    int    cnt  = deg[n];
    int    cntp = (cnt + 7) & ~7;
    float2 self = ald2[n];          // {al2[n], dinv[n]}
    float  di   = self.y;
    float  arn  = ar2[n];

    float acc = 0.0f;
    for (int j = 0; j < cntp; j += 8) {
        int sv[8]; float av[8], vv[8];
        #pragma unroll
        for (int t = 0; t < 8; t++) {
            sv[t] = max(srcs[s0 + j + t], 0);
            av[t] = alphas[s0 + j + t];
        }
        #pragma unroll
        for (int t = 0; t < 8; t++) vv[t] = bf2f(h1b[(size_t)sv[t] * 64 + lane]);
        #pragma unroll
        for (int t = 0; t < 8; t++) acc = fmaf(vv[t], av[t], acc);
    }

    float selfa = fast_tanh(self.x + arn) * di * di;
    float h1l   = bf2f(h1b[(size_t)n * 64 + lane]);
    float xnl   = bf2f(xb[(size_t)n * 64 + lane]);
    float v = acc + selfa * h1l + EPS * xnl;
    x2[(size_t)n * 64 + lane] = sqrtf(v * v + 1e-8f);
}

// ---------------------------------------------------------------------------
// K7: per-user CSR segment sum
// ---------------------------------------------------------------------------
__global__ void k_usersum(const float* __restrict__ x2, const int* __restrict__ offs,
                          float* __restrict__ x3, int U)
{
    int u    = blockIdx.x;
    int lane = threadIdx.x;
    if (u >= U) return;
    int s = offs[u], e = offs[u + 1];
    float acc = 0.0f;
    for (int n = s; n < e; n++) acc += x2[(size_t)n * 64 + lane];
    x3[(size_t)u * 64 + lane] = acc;
}

// ---------------------------------------------------------------------------
// K8: head
// ---------------------------------------------------------------------------
__global__ void k_head(const float* __restrict__ x3, const int* __restrict__ re_index,
                       const float* __restrict__ W_f1, const float* __restrict__ b_f1,
                       const float* __restrict__ W_lab, const float* __restrict__ b_lab,
                       float* __restrict__ out, int U)
{
    int u = blockIdx.x * blockDim.x + threadIdx.x;
    if (u >= U) return;
    int r = re_index[u];
    const float* y = x3 + (size_t)r * 64;
    float yv[64];
    #pragma unroll
    for (int k = 0; k < 64; k++) yv[k] = y[k];
    float o0 = b_lab[0], o1 = b_lab[1];
    for (int j = 0; j < 32; j++) {
        float s = b_f1[j];
        #pragma unroll 8
        for (int k = 0; k < 64; k++) s = fmaf(yv[k], W_f1[k * 32 + j], s);
        s = LRELU(s);
        o0 = fmaf(s, W_lab[j * 2 + 0], o0);
        o1 = fmaf(s, W_lab[j * 2 + 1], o1);
    }
    out[(size_t)u * 2 + 0] = o0;
    out[(size_t)u * 2 + 1] = o1;
}

// ---------------------------------------------------------------------------
extern "C" void kernel_launch(void* const* d_in, const int* in_sizes, int n_in,
                              void* d_out, int out_size, void* d_ws, size_t ws_size,
                              hipStream_t stream)
{
    const float* num_prop = (const float*)d_in[0];
    const float* cat_prop = (const float*)d_in[1];
    const int*   offs     = (const int*)d_in[2];
    const int*   edge     = (const int*)d_in[3];
    const int*   re_index = (const int*)d_in[4];
    const float* W_num    = (const float*)d_in[5];
    const float* b_num    = (const float*)d_in[6];
    const float* W_cat    = (const float*)d_in[7];
    const float* b_cat    = (const float*)d_in[8];
    const float* W_tog    = (const float*)d_in[9];
    const float* b_tog    = (const float*)d_in[10];
    const float* att_l    = (const float*)d_in[11];
    const float* att_r    = (const float*)d_in[12];
    const float* W_f1     = (const float*)d_in[13];
    const float* b_f1     = (const float*)d_in[14];
    const float* W_lab    = (const float*)d_in[15];
    const float* b_lab    = (const float*)d_in[16];

    const int N = in_sizes[0] / 20;
    const int E = in_sizes[3] / 2;
    const int U = in_sizes[4];

    const int* src = edge;       // edge_index[0]
    const int* dst = edge + E;   // edge_index[1]

    const int    NB      = (N + 1023) >> 10;                   // dst buckets
    const size_t srcsCap = (size_t)E + 7ull * (size_t)N + 64;  // padded CSR capacity

    // workspace carve-up (4-byte units; int2/float2 8B-aligned by layout)
    float* ws = (float*)d_ws;
    size_t off = 0;
    unsigned short* xb  = (unsigned short*)(ws + off); off += (size_t)N * 32;  // bf16 x
    unsigned short* h1b = (unsigned short*)(ws + off); off += (size_t)N * 32;  // bf16 h1
    float*  B    = ws + off; off += (size_t)N * 64;   // x2 (fp32)
    float2* ald1 = (float2*)(ws + off); off += (size_t)N * 2;
    float2* ald2 = (float2*)(ws + off); off += (size_t)N * 2;
    int2*   buckets = (int2*)(ws + off); off += (size_t)NB * BIN_CAP * 2;
    float*  al   = ws + off; off += N;
    float*  ar   = ws + off; off += N;
    float*  ar2  = ws + off; off += N;
    float*  x3   = ws + off; off += (size_t)U * 64;
    unsigned short* Wb = (unsigned short*)(ws + off); off += 2048;  // 4096 bf16
    int*    deg        = (int*)(ws + off); off += N;
    int*    row_start  = (int*)(ws + off); off += N;
    int*    bucket_cnt = (int*)(ws + off); off += NB;
    int*    srcs       = (int*)(ws + off); off += srcsCap;
    int*    dsts       = (int*)(ws + off); off += srcsCap;
    float*  alphas     = (float*)(ws + off); off += srcsCap;
    int*    blockSums  = (int*)(ws + off); off += 256;

    hipMemsetAsync(bucket_cnt, 0, (size_t)NB * 4, stream);
    hipMemsetAsync(srcs, 0xFF, srcsCap * 4, stream);   // padding slots = -1
    hipMemsetAsync(alphas, 0, srcsCap * 4, stream);    // padding alphas = 0

    const int nbN4   = (N + 3) / 4;          // wave-per-node kernels, 4 nodes/block
    const int nbScan = (N + 1023) / 1024;    // <= 256 required by k_scan2
    const int nbBin  = (E + BIN_EPB - 1) / BIN_EPB;
    const int nbCap  = (int)((srcsCap + 255) / 256);

    // pack W_tog into MFMA B-fragment bf16 layout (tiny, once per call)
    k_prep<<<1, 256, 0, stream>>>(W_tog, Wb);

    // MFMA feature MLP: block = 64 nodes
    k_feat<<<(N + 63) / 64, 256, 0, stream>>>(num_prop, cat_prop, W_num, b_num,
                                              W_cat, b_cat, Wb, b_tog,
                                              att_l, att_r, xb, al, ar, N);

    // radix partition phase 1 (no global atomics)
    k_bin<<<nbBin, 256, 0, stream>>>(src, dst, bucket_cnt, buckets, E, NB);

    // per-bucket degree histogram (LDS counters, coalesced deg write)
    k_degB<<<NB, 1024, 0, stream>>>(buckets, bucket_cnt, deg, N);

    // padded CSR offsets
    k_scan1<<<nbScan, 1024, 0, stream>>>(deg, row_start, blockSums, N);
    k_scan2<<<1, 256, 0, stream>>>(blockSums, nbScan);
    k_scan3<<<(N + 255) / 256, 256, 0, stream>>>(row_start, blockSums, deg, al, ald1, N);

    // radix partition phase 2: bucket-local CSR fill + fused layer-1 alpha
    k_fill2<<<NB, 1024, 0, stream>>>(buckets, bucket_cnt, row_start, ald1, ar,
                                     srcs, dsts, alphas);

    // ---- FAConv layer 1 (h = h0 = x): scalar-offload gather ----
    k_gather1<<<nbN4, 256, 0, stream>>>(srcs, alphas, row_start, deg, xb, ald1, ar,
                                        att_l, att_r, h1b, ald2, ar2, N);

    // ---- FAConv layer 2 (h = h1, h0 = x) ----
    k_alphaE<<<nbCap, 256, 0, stream>>>(srcs, dsts, ald2, ar2, alphas, (int)srcsCap);
    k_gather2<<<nbN4, 256, 0, stream>>>(srcs, alphas, row_start, deg, h1b, xb,
                                        ald2, ar2, B, N);

    // ---- per-user pooling + head ----
    k_usersum<<<U, 64, 0, stream>>>(B, offs, x3, U);
    k_head<<<(U + 255) / 256, 256, 0, stream>>>(x3, re_index, W_f1, b_f1, W_lab, b_lab,
                                                (float*)d_out, U);
}

// Round 16
// 479.362 us; speedup vs baseline: 1.1451x; 1.0850x over previous
//
#include <hip/hip_runtime.h>
#include <hip/hip_bf16.h>

#define LRELU(v) ((v) > 0.0f ? (v) : 0.01f * (v))
#define EPS 0.1f

#define BIN_EPB 2048        // edges per k_bin block
#define BIN_CAP 12288       // bucket capacity (expected 8163, +45 sigma headroom)

typedef __attribute__((ext_vector_type(8))) short bf16x8;
typedef __attribute__((ext_vector_type(4))) float f32x4;

// fast tanh via v_exp_f32 + v_rcp_f32: ~1e-7 abs err, saturates correctly
__device__ __forceinline__ float fast_tanh(float v)
{
    float e = __expf(2.0f * v);
    return 1.0f - 2.0f * __builtin_amdgcn_rcpf(e + 1.0f);
}

// bf16 <-> f32 (RNE pack); feature rows stored bf16 to halve gather traffic
__device__ __forceinline__ float bf2f(unsigned short h)
{
    return __uint_as_float(((unsigned int)h) << 16);
}
__device__ __forceinline__ unsigned short f2bf(float f)
{
    unsigned int u = __float_as_uint(f);
    u += 0x7FFFu + ((u >> 16) & 1u);
    return (unsigned short)(u >> 16);
}

// ---------------------------------------------------------------------------
// K0: pack weights into bf16 MFMA B-fragment order (lane l, elem j ->
// B[k=(l>>4)*8+j][n=(l&15)]; layout verified by round-15 layer-2 absmax).
// Wb : W_tog as 2 k-tiles x 4 n-tiles.
// Wb1: layer-1 block-diag Wfull = [[W_num,0],[0,W_cat]] (K=32), 4 n-tiles.
// ---------------------------------------------------------------------------
__global__ void k_prep(const float* __restrict__ W_num, const float* __restrict__ W_cat,
                       const float* __restrict__ W_tog,
                       unsigned short* __restrict__ Wb, unsigned short* __restrict__ Wb1)
{
    int t = threadIdx.x;            // one block, 256 threads
    for (int i = t; i < 8 * 512; i += 256) {
        int tile = i >> 9;          // kt*4+nt
        int kt   = tile >> 2, nt = tile & 3;
        int lane = (i >> 3) & 63;
        int j    = i & 7;
        int k    = kt * 32 + (lane >> 4) * 8 + j;
        int n    = nt * 16 + (lane & 15);
        Wb[i] = f2bf(W_tog[k * 64 + n]);
    }
    for (int i = t; i < 4 * 512; i += 256) {
        int nt   = i >> 9;
        int lane = (i >> 3) & 63;
        int j    = i & 7;
        int k    = (lane >> 4) * 8 + j;     // 0..31
        int n    = nt * 16 + (lane & 15);   // 0..63
        float w;
        if (n < 32) w = (k < 20)  ? W_num[k * 32 + n]              : 0.0f;
        else        w = (k >= 20) ? W_cat[(k - 20) * 32 + (n - 32)] : 0.0f;
        Wb1[i] = f2bf(w);
    }
}

// ---------------------------------------------------------------------------
// K1: per-node feature MLP, block = 64 nodes (4 waves x 16 nodes), both
// layers on MFMA. Inputs staged coalesced to LDS as bf16 [64][32] (pitch 40);
// layer 1 = [16,32]@[32,64] block-diag MFMA (1 A-frag ds_read + 4 mfma);
// layer 2 = [16,64]@[64,64] (2 k-steps x 4 n-tiles, prepacked Wb).
// D layout: col=lane&15 (out-ch), row=quad*4+reg (node) — m89-verified.
// mid roundtrips through LDS (same-wave rows; lgkmcnt ordering suffices).
// (History: thread-per-node mid[64] spilled (r9/12/13); readlane form was
// VALU-bound (r14); serial-s_load layer 1 was latency-bound at 77us (r15).)
// ---------------------------------------------------------------------------
__global__ void __launch_bounds__(256)
k_feat(const float* __restrict__ num_prop,
       const float* __restrict__ cat_prop,
       const unsigned short* __restrict__ Wb1,
       const float* __restrict__ b_num, const float* __restrict__ b_cat,
       const unsigned short* __restrict__ Wb, const float* __restrict__ b_tog,
       const float* __restrict__ att_l, const float* __restrict__ att_r,
       unsigned short* __restrict__ xb,
       float* __restrict__ al, float* __restrict__ ar, int N)
{
    __shared__ unsigned short in_lds[64][40];   // bf16 inputs (32 used), pad 8
    __shared__ unsigned short mid[64][72];      // bf16 mid, pad 8

    int tid  = threadIdx.x;
    int lane = tid & 63;
    int w    = tid >> 6;                        // wave 0..3
    int blockStart = blockIdx.x * 64;

    // ---- stage inputs coalesced (clamped tail duplicates last node) ----
    for (int i = tid; i < 64 * 20; i += 256) {
        int node = i / 20, k = i % 20;
        int n = min(blockStart + node, N - 1);
        in_lds[node][k] = f2bf(num_prop[(size_t)n * 20 + k]);
    }
    for (int i = tid; i < 64 * 12; i += 256) {
        int node = i / 12, k = i % 12;
        int n = min(blockStart + node, N - 1);
        in_lds[node][20 + k] = f2bf(cat_prop[(size_t)n * 12 + k]);
    }
    __syncthreads();

    int q   = lane >> 4;                        // quad
    int c16 = lane & 15;

    // ---- layer 1: one MFMA per n-tile ----
    bf16x8 ain = *(const bf16x8*)&in_lds[w * 16 + c16][q * 8];
    #pragma unroll
    for (int nt = 0; nt < 4; nt++) {
        bf16x8 b = *(const bf16x8*)&Wb1[nt * 512 + lane * 8];
        f32x4 acc = {0.0f, 0.0f, 0.0f, 0.0f};
        acc = __builtin_amdgcn_mfma_f32_16x16x32_bf16(ain, b, acc, 0, 0, 0);
        int   ch   = nt * 16 + c16;
        float bias = (ch < 32) ? b_num[ch] : b_cat[ch - 32];
        #pragma unroll
        for (int r = 0; r < 4; r++) {
            float s = acc[r] + bias;
            s = LRELU(s);
            mid[w * 16 + q * 4 + r][ch] = f2bf(s);
        }
    }
    // same-wave LDS write->read: compiler's lgkmcnt wait orders this

    // ---- layer 2: MFMA (2 k-steps x 4 n-tiles) ----
    bf16x8 a0 = *(const bf16x8*)&mid[w * 16 + c16][q * 8];        // k 0..31
    bf16x8 a1 = *(const bf16x8*)&mid[w * 16 + c16][32 + q * 8];   // k 32..63

    float pal[4] = {0, 0, 0, 0};
    float par[4] = {0, 0, 0, 0};

    #pragma unroll
    for (int nt = 0; nt < 4; nt++) {
        bf16x8 b0 = *(const bf16x8*)&Wb[(0 * 4 + nt) * 512 + lane * 8];
        bf16x8 b1 = *(const bf16x8*)&Wb[(1 * 4 + nt) * 512 + lane * 8];
        f32x4 acc = {0.0f, 0.0f, 0.0f, 0.0f};
        acc = __builtin_amdgcn_mfma_f32_16x16x32_bf16(a0, b0, acc, 0, 0, 0);
        acc = __builtin_amdgcn_mfma_f32_16x16x32_bf16(a1, b1, acc, 0, 0, 0);

        int   ch  = nt * 16 + c16;
        float bt  = b_tog[ch];
        float atl = att_l[ch];
        float atr = att_r[ch];
        #pragma unroll
        for (int r = 0; r < 4; r++) {
            float s = acc[r] + bt;
            s = LRELU(s);
            int n = blockStart + w * 16 + q * 4 + r;
            if (n < N) xb[(size_t)n * 64 + ch] = f2bf(s);
            pal[r] = fmaf(s, atl, pal[r]);
            par[r] = fmaf(s, atr, par[r]);
        }
    }

    // reduce al/ar across the 16 lanes of each quad (xor<16 stays in-quad)
    #pragma unroll
    for (int r = 0; r < 4; r++) {
        float pl = pal[r], pr = par[r];
        #pragma unroll
        for (int off = 8; off > 0; off >>= 1) {
            pl += __shfl_xor(pl, off);
            pr += __shfl_xor(pr, off);
        }
        int n = blockStart + w * 16 + q * 4 + r;
        if (c16 == 0 && n < N) { al[n] = pl; ar[n] = pr; }
    }
}

// ---------------------------------------------------------------------------
// K2: radix partition phase 1 (no global atomics).
// ---------------------------------------------------------------------------
__global__ void k_bin(const int* __restrict__ src, const int* __restrict__ dst,
                      int* __restrict__ bucket_cnt,
                      int2* __restrict__ buckets, int E, int NB)
{
    __shared__ int  hist[256];
    __shared__ int  lbase[256];
    __shared__ int  gbase[256];
    __shared__ int2 stage[BIN_EPB];

    int tid  = threadIdx.x;          // blockDim = 256
    int base = blockIdx.x * BIN_EPB;

    hist[tid] = 0;
    __syncthreads();

    int s[8], d[8], rk[8];
    #pragma unroll
    for (int k = 0; k < 8; k++) {
        int e = base + k * 256 + tid;
        s[k] = -1;
        if (e < E) {
            s[k] = src[e];
            d[k] = dst[e];
            rk[k] = atomicAdd(&hist[d[k] >> 10], 1);
        }
    }
    __syncthreads();

    int v = hist[tid];
    lbase[tid] = v;
    __syncthreads();
    for (int off = 1; off < 256; off <<= 1) {
        int t = (tid >= off) ? lbase[tid - off] : 0;
        __syncthreads();
        lbase[tid] += t;
        __syncthreads();
    }
    int incl = lbase[tid];
    __syncthreads();
    lbase[tid] = incl - v;
    if (tid < NB && v > 0) gbase[tid] = atomicAdd(&bucket_cnt[tid], v);
    __syncthreads();

    #pragma unroll
    for (int k = 0; k < 8; k++) {
        if (s[k] >= 0) {
            int b = d[k] >> 10;
            stage[lbase[b] + rk[k]] = make_int2(s[k], d[k]);
        }
    }
    __syncthreads();

    int tot = min(BIN_EPB, E - base);
    for (int i = tid; i < tot; i += 256) {
        int2 p = stage[i];
        int b = p.y >> 10;
        buckets[(size_t)b * BIN_CAP + gbase[b] + (i - lbase[b])] = p;
    }
}

// ---------------------------------------------------------------------------
// K2b: per-bucket degree histogram (LDS counters, coalesced deg write).
// ---------------------------------------------------------------------------
__global__ void k_degB(const int2* __restrict__ buckets, const int* __restrict__ bucket_cnt,
                       int* __restrict__ deg, int N)
{
    __shared__ int cur[1024];
    int b   = blockIdx.x;
    int tid = threadIdx.x;          // blockDim = 1024
    cur[tid] = 0;
    __syncthreads();

    int cnt = bucket_cnt[b];
    const int2* bp = buckets + (size_t)b * BIN_CAP;
    for (int i = tid; i < cnt; i += 1024)
        atomicAdd(&cur[bp[i].y & 1023], 1);
    __syncthreads();

    int n = b * 1024 + tid;
    if (n < N) deg[n] = cur[tid];
}

// ---------------------------------------------------------------------------
// CSR scan over PADDED row lengths ((deg+7)&~7).
// ---------------------------------------------------------------------------
__global__ void k_scan1(const int* __restrict__ deg, int* __restrict__ row_start,
                        int* __restrict__ blockSums, int N)
{
    __shared__ int sh[1024];
    int tid = threadIdx.x;
    int i = blockIdx.x * 1024 + tid;
    int v = (i < N) ? ((deg[i] + 7) & ~7) : 0;      // padded length
    sh[tid] = v;
    __syncthreads();
    #pragma unroll
    for (int off = 1; off < 1024; off <<= 1) {
        int t = (tid >= off) ? sh[tid - off] : 0;
        __syncthreads();
        sh[tid] += t;
        __syncthreads();
    }
    if (i < N) row_start[i] = sh[tid] - v;          // exclusive within block
    if (tid == 1023) blockSums[blockIdx.x] = sh[1023];
}

__global__ void k_scan2(int* __restrict__ blockSums, int nb)
{
    __shared__ int sh[256];
    int tid = threadIdx.x;
    int v = (tid < nb) ? blockSums[tid] : 0;
    sh[tid] = v;
    __syncthreads();
    #pragma unroll
    for (int off = 1; off < 256; off <<= 1) {
        int t = (tid >= off) ? sh[tid - off] : 0;
        __syncthreads();
        sh[tid] += t;
        __syncthreads();
    }
    if (tid < nb) blockSums[tid] = sh[tid] - v;     // exclusive
}

// row_start += block offset; pack ald1 = {al, rsqrt(deg+1)}
__global__ void k_scan3(int* __restrict__ row_start, const int* __restrict__ blockSums,
                        const int* __restrict__ deg,
                        const float* __restrict__ al, float2* __restrict__ ald1, int N)
{
    int i = blockIdx.x * blockDim.x + threadIdx.x;
    if (i >= N) return;
    row_start[i] += blockSums[i >> 10];
    float dv = 1.0f / sqrtf((float)deg[i] + 1.0f);   // +1 self-loop
    ald1[i]  = make_float2(al[i], dv);
}

// ---------------------------------------------------------------------------
// K4: radix partition phase 2: bucket-local CSR fill (LDS cursors) + fused
// layer-1 alpha. Padding alphas slots are pre-memset to 0.
// ---------------------------------------------------------------------------
__global__ void k_fill2(const int2* __restrict__ buckets, const int* __restrict__ bucket_cnt,
                        const int* __restrict__ row_start,
                        const float2* __restrict__ ald, const float* __restrict__ arr,
                        int* __restrict__ srcs, int* __restrict__ dsts,
                        float* __restrict__ alphas)
{
    __shared__ int cur[1024];
    int b   = blockIdx.x;
    int tid = threadIdx.x;          // blockDim = 1024
    cur[tid] = 0;
    __syncthreads();

    int cnt = bucket_cnt[b];
    const int2* bp = buckets + (size_t)b * BIN_CAP;
    for (int i = tid; i < cnt; i += 1024) {
        int2 p = bp[i];
        int r = p.y & 1023;
        int o = atomicAdd(&cur[r], 1);
        int pos = row_start[p.y] + o;
        float2 as = ald[p.x];           // random 8B (L2/L3)
        float2 ad = ald[p.y];           // bucket-local
        srcs[pos]   = p.x;
        dsts[pos]   = p.y;
        alphas[pos] = fast_tanh(as.x + arr[p.y]) * as.y * ad.y;
    }
}

// ---------------------------------------------------------------------------
// K4b: edge-parallel alpha in CSR order (layer 2 only).
// ---------------------------------------------------------------------------
__global__ void k_alphaE(const int* __restrict__ srcs, const int* __restrict__ dsts,
                         const float2* __restrict__ ald, const float* __restrict__ arr,
                         float* __restrict__ alphas, int P)
{
    int p = blockIdx.x * blockDim.x + threadIdx.x;
    if (p >= P) return;
    int s = srcs[p];
    float a = 0.0f;
    if (s >= 0) {
        int d = dsts[p];
        float2 as = ald[s];
        float2 ad = ald[d];
        a = fast_tanh(as.x + arr[d]) * as.y * ad.y;
    }
    alphas[p] = a;
}

// ---------------------------------------------------------------------------
// K5: gather layer 1: wave-uniform n (readfirstlane) -> srcs/alphas on the
// scalar pipe, per-edge VALU = load+cvt+fma. Rows padded to x8. Fused
// finalize + al2/ar2 reductions; epilogue packs ald2 = {al2, dinv}.
// ---------------------------------------------------------------------------
__global__ void k_gather1(const int* __restrict__ srcs, const float* __restrict__ alphas,
                          const int* __restrict__ row_start, const int* __restrict__ deg,
                          const unsigned short* __restrict__ xb,
                          const float2* __restrict__ ald1, const float* __restrict__ ar,
                          const float* __restrict__ att_l, const float* __restrict__ att_r,
                          unsigned short* __restrict__ h1b, float2* __restrict__ ald2,
                          float* __restrict__ ar2, int N)
{
    int lane = threadIdx.x & 63;
    int n    = __builtin_amdgcn_readfirstlane(blockIdx.x * 4 + (threadIdx.x >> 6));
    if (n >= N) return;

    int    s0   = row_start[n];
    int    cnt  = deg[n];
    int    cntp = (cnt + 7) & ~7;
    float2 self = ald1[n];          // {al[n], dinv[n]}
    float  di   = self.y;
    float  arn  = ar[n];

    float acc = 0.0f;
    for (int j = 0; j < cntp; j += 8) {
        int sv[8]; float av[8], vv[8];
        #pragma unroll
        for (int t = 0; t < 8; t++) {
            sv[t] = max(srcs[s0 + j + t], 0);     // scalar: padding -> row 0
            av[t] = alphas[s0 + j + t];           // scalar: padding -> 0
        }
        #pragma unroll
        for (int t = 0; t < 8; t++) vv[t] = bf2f(xb[(size_t)sv[t] * 64 + lane]);
        #pragma unroll
        for (int t = 0; t < 8; t++) acc = fmaf(vv[t], av[t], acc);
    }

    float selfa = fast_tanh(self.x + arn) * di * di;
    float xnl   = bf2f(xb[(size_t)n * 64 + lane]);
    float v     = acc + (selfa + EPS) * xnl;

    float pl = v * att_l[lane];
    float pr = v * att_r[lane];
    #pragma unroll
    for (int off = 32; off > 0; off >>= 1) {
        pl += __shfl_down(pl, off);
        pr += __shfl_down(pr, off);
    }
    h1b[(size_t)n * 64 + lane] = f2bf(v);
    if (lane == 0) { ald2[n] = make_float2(pl, di); ar2[n] = pr; }
}

// ---------------------------------------------------------------------------
// K6: gather layer 2, same structure, fused finalize + abs-smooth.
// ---------------------------------------------------------------------------
__global__ void k_gather2(const int* __restrict__ srcs, const float* __restrict__ alphas,
                          const int* __restrict__ row_start, const int* __restrict__ deg,
                          const unsigned short* __restrict__ h1b,
                          const unsigned short* __restrict__ xb,
                          const float2* __restrict__ ald2, const float* __restrict__ ar2,
                          float* __restrict__ x2, int N)
{
    int lane = threadIdx.x & 63;
    int n    = __builtin_amdgcn_readfirstlane(blockIdx.x * 4 + (threadIdx.x >> 6));
    if (n >= N) return;

    int    s0   = row_start[n];
    int    cnt  = deg[n];
    int    cntp = (cnt + 7) & ~7;
    float2 self = ald2[n];          // {al2[n], dinv[n]}
    float  di   = self.y;
    float  arn  = ar2[n];

    float acc = 0.0f;
    for (int j = 0; j < cntp; j += 8) {
        int sv[8]; float av[8], vv[8];
        #pragma unroll
        for (int t = 0; t < 8; t++) {
            sv[t] = max(srcs[s0 + j + t], 0);
            av[t] = alphas[s0 + j + t];
        }
        #pragma unroll
        for (int t = 0; t < 8; t++) vv[t] = bf2f(h1b[(size_t)sv[t] * 64 + lane]);
        #pragma unroll
        for (int t = 0; t < 8; t++) acc = fmaf(vv[t], av[t], acc);
    }

    float selfa = fast_tanh(self.x + arn) * di * di;
    float h1l   = bf2f(h1b[(size_t)n * 64 + lane]);
    float xnl   = bf2f(xb[(size_t)n * 64 + lane]);
    float v = acc + selfa * h1l + EPS * xnl;
    x2[(size_t)n * 64 + lane] = sqrtf(v * v + 1e-8f);
}

// ---------------------------------------------------------------------------
// K7: per-user CSR segment sum
// ---------------------------------------------------------------------------
__global__ void k_usersum(const float* __restrict__ x2, const int* __restrict__ offs,
                          float* __restrict__ x3, int U)
{
    int u    = blockIdx.x;
    int lane = threadIdx.x;
    if (u >= U) return;
    int s = offs[u], e = offs[u + 1];
    float acc = 0.0f;
    for (int n = s; n < e; n++) acc += x2[(size_t)n * 64 + lane];
    x3[(size_t)u * 64 + lane] = acc;
}

// ---------------------------------------------------------------------------
// K8: head
// ---------------------------------------------------------------------------
__global__ void k_head(const float* __restrict__ x3, const int* __restrict__ re_index,
                       const float* __restrict__ W_f1, const float* __restrict__ b_f1,
                       const float* __restrict__ W_lab, const float* __restrict__ b_lab,
                       float* __restrict__ out, int U)
{
    int u = blockIdx.x * blockDim.x + threadIdx.x;
    if (u >= U) return;
    int r = re_index[u];
    const float* y = x3 + (size_t)r * 64;
    float yv[64];
    #pragma unroll
    for (int k = 0; k < 64; k++) yv[k] = y[k];
    float o0 = b_lab[0], o1 = b_lab[1];
    for (int j = 0; j < 32; j++) {
        float s = b_f1[j];
        #pragma unroll 8
        for (int k = 0; k < 64; k++) s = fmaf(yv[k], W_f1[k * 32 + j], s);
        s = LRELU(s);
        o0 = fmaf(s, W_lab[j * 2 + 0], o0);
        o1 = fmaf(s, W_lab[j * 2 + 1], o1);
    }
    out[(size_t)u * 2 + 0] = o0;
    out[(size_t)u * 2 + 1] = o1;
}

// ---------------------------------------------------------------------------
extern "C" void kernel_launch(void* const* d_in, const int* in_sizes, int n_in,
                              void* d_out, int out_size, void* d_ws, size_t ws_size,
                              hipStream_t stream)
{
    const float* num_prop = (const float*)d_in[0];
    const float* cat_prop = (const float*)d_in[1];
    const int*   offs     = (const int*)d_in[2];
    const int*   edge     = (const int*)d_in[3];
    const int*   re_index = (const int*)d_in[4];
    const float* W_num    = (const float*)d_in[5];
    const float* b_num    = (const float*)d_in[6];
    const float* W_cat    = (const float*)d_in[7];
    const float* b_cat    = (const float*)d_in[8];
    const float* W_tog    = (const float*)d_in[9];
    const float* b_tog    = (const float*)d_in[10];
    const float* att_l    = (const float*)d_in[11];
    const float* att_r    = (const float*)d_in[12];
    const float* W_f1     = (const float*)d_in[13];
    const float* b_f1     = (const float*)d_in[14];
    const float* W_lab    = (const float*)d_in[15];
    const float* b_lab    = (const float*)d_in[16];

    const int N = in_sizes[0] / 20;
    const int E = in_sizes[3] / 2;
    const int U = in_sizes[4];

    const int* src = edge;       // edge_index[0]
    const int* dst = edge + E;   // edge_index[1]

    const int    NB      = (N + 1023) >> 10;                   // dst buckets
    const size_t srcsCap = (size_t)E + 7ull * (size_t)N + 64;  // padded CSR capacity

    // workspace carve-up (4-byte units; int2/float2 8B-aligned by layout)
    float* ws = (float*)d_ws;
    size_t off = 0;
    unsigned short* xb  = (unsigned short*)(ws + off); off += (size_t)N * 32;  // bf16 x
    unsigned short* h1b = (unsigned short*)(ws + off); off += (size_t)N * 32;  // bf16 h1
    float*  B    = ws + off; off += (size_t)N * 64;   // x2 (fp32)
    float2* ald1 = (float2*)(ws + off); off += (size_t)N * 2;
    float2* ald2 = (float2*)(ws + off); off += (size_t)N * 2;
    int2*   buckets = (int2*)(ws + off); off += (size_t)NB * BIN_CAP * 2;
    float*  al   = ws + off; off += N;
    float*  ar   = ws + off; off += N;
    float*  ar2  = ws + off; off += N;
    float*  x3   = ws + off; off += (size_t)U * 64;
    unsigned short* Wb  = (unsigned short*)(ws + off); off += 2048;  // 4096 bf16
    unsigned short* Wb1 = (unsigned short*)(ws + off); off += 1024;  // 2048 bf16
    int*    deg        = (int*)(ws + off); off += N;
    int*    row_start  = (int*)(ws + off); off += N;
    int*    bucket_cnt = (int*)(ws + off); off += NB;
    int*    srcs       = (int*)(ws + off); off += srcsCap;
    int*    dsts       = (int*)(ws + off); off += srcsCap;
    float*  alphas     = (float*)(ws + off); off += srcsCap;
    int*    blockSums  = (int*)(ws + off); off += 256;

    hipMemsetAsync(bucket_cnt, 0, (size_t)NB * 4, stream);
    hipMemsetAsync(srcs, 0xFF, srcsCap * 4, stream);   // padding slots = -1
    hipMemsetAsync(alphas, 0, srcsCap * 4, stream);    // padding alphas = 0

    const int nbN4   = (N + 3) / 4;          // wave-per-node kernels, 4 nodes/block
    const int nbScan = (N + 1023) / 1024;    // <= 256 required by k_scan2
    const int nbBin  = (E + BIN_EPB - 1) / BIN_EPB;
    const int nbCap  = (int)((srcsCap + 255) / 256);

    // pack both weight matrices into MFMA B-fragment bf16 layout
    k_prep<<<1, 256, 0, stream>>>(W_num, W_cat, W_tog, Wb, Wb1);

    // all-MFMA feature MLP: block = 64 nodes
    k_feat<<<(N + 63) / 64, 256, 0, stream>>>(num_prop, cat_prop, Wb1, b_num, b_cat,
                                              Wb, b_tog, att_l, att_r, xb, al, ar, N);

    // radix partition phase 1 (no global atomics)
    k_bin<<<nbBin, 256, 0, stream>>>(src, dst, bucket_cnt, buckets, E, NB);

    // per-bucket degree histogram (LDS counters, coalesced deg write)
    k_degB<<<NB, 1024, 0, stream>>>(buckets, bucket_cnt, deg, N);

    // padded CSR offsets
    k_scan1<<<nbScan, 1024, 0, stream>>>(deg, row_start, blockSums, N);
    k_scan2<<<1, 256, 0, stream>>>(blockSums, nbScan);
    k_scan3<<<(N + 255) / 256, 256, 0, stream>>>(row_start, blockSums, deg, al, ald1, N);

    // radix partition phase 2: bucket-local CSR fill + fused layer-1 alpha
    k_fill2<<<NB, 1024, 0, stream>>>(buckets, bucket_cnt, row_start, ald1, ar,
                                     srcs, dsts, alphas);

    // ---- FAConv layer 1 (h = h0 = x): scalar-offload gather ----
    k_gather1<<<nbN4, 256, 0, stream>>>(srcs, alphas, row_start, deg, xb, ald1, ar,
                                        att_l, att_r, h1b, ald2, ar2, N);

    // ---- FAConv layer 2 (h = h1, h0 = x) ----
    k_alphaE<<<nbCap, 256, 0, stream>>>(srcs, dsts, ald2, ar2, alphas, (int)srcsCap);
    k_gather2<<<nbN4, 256, 0, stream>>>(srcs, alphas, row_start, deg, h1b, xb,
                                        ald2, ar2, B, N);

    // ---- per-user pooling + head ----
    k_usersum<<<U, 64, 0, stream>>>(B, offs, x3, U);
    k_head<<<(U + 255) / 256, 256, 0, stream>>>(x3, re_index, W_f1, b_f1, W_lab, b_lab,
                                                (float*)d_out, U);
}

// Round 17
// 478.622 us; speedup vs baseline: 1.1468x; 1.0015x over previous
//
#include <hip/hip_runtime.h>
#include <hip/hip_bf16.h>

#define LRELU(v) ((v) > 0.0f ? (v) : 0.01f * (v))
#define EPS 0.1f

#define BSHIFT  9           // 512-node buckets -> NB ~391 blocks (~1.5/CU)
#define BSIZE   512
#define BIN_EPB 2048        // edges per k_bin block
#define BIN_CAP 6144        // bucket capacity (expected ~4092, wide headroom)

typedef __attribute__((ext_vector_type(8))) short bf16x8;
typedef __attribute__((ext_vector_type(4))) float f32x4;

// fast tanh via v_exp_f32 + v_rcp_f32: ~1e-7 abs err, saturates correctly
__device__ __forceinline__ float fast_tanh(float v)
{
    float e = __expf(2.0f * v);
    return 1.0f - 2.0f * __builtin_amdgcn_rcpf(e + 1.0f);
}

__device__ __forceinline__ float bf2f(unsigned short h)
{
    return __uint_as_float(((unsigned int)h) << 16);
}
__device__ __forceinline__ unsigned short f2bf(float f)
{
    unsigned int u = __float_as_uint(f);
    u += 0x7FFFu + ((u >> 16) & 1u);
    return (unsigned short)(u >> 16);
}

// ---------------------------------------------------------------------------
// K0: pack weights into bf16 MFMA B-fragment order (verified r15/r16).
// ---------------------------------------------------------------------------
__global__ void k_prep(const float* __restrict__ W_num, const float* __restrict__ W_cat,
                       const float* __restrict__ W_tog,
                       unsigned short* __restrict__ Wb, unsigned short* __restrict__ Wb1)
{
    int t = threadIdx.x;            // one block, 256 threads
    for (int i = t; i < 8 * 512; i += 256) {
        int tile = i >> 9;          // kt*4+nt
        int kt   = tile >> 2, nt = tile & 3;
        int lane = (i >> 3) & 63;
        int j    = i & 7;
        int k    = kt * 32 + (lane >> 4) * 8 + j;
        int n    = nt * 16 + (lane & 15);
        Wb[i] = f2bf(W_tog[k * 64 + n]);
    }
    for (int i = t; i < 4 * 512; i += 256) {
        int nt   = i >> 9;
        int lane = (i >> 3) & 63;
        int j    = i & 7;
        int k    = (lane >> 4) * 8 + j;     // 0..31
        int n    = nt * 16 + (lane & 15);   // 0..63
        float w;
        if (n < 32) w = (k < 20)  ? W_num[k * 32 + n]              : 0.0f;
        else        w = (k >= 20) ? W_cat[(k - 20) * 32 + (n - 32)] : 0.0f;
        Wb1[i] = f2bf(w);
    }
}

// ---------------------------------------------------------------------------
// K1: all-MFMA feature MLP, block = 64 nodes (r16-verified).
// ---------------------------------------------------------------------------
__global__ void __launch_bounds__(256)
k_feat(const float* __restrict__ num_prop,
       const float* __restrict__ cat_prop,
       const unsigned short* __restrict__ Wb1,
       const float* __restrict__ b_num, const float* __restrict__ b_cat,
       const unsigned short* __restrict__ Wb, const float* __restrict__ b_tog,
       const float* __restrict__ att_l, const float* __restrict__ att_r,
       unsigned short* __restrict__ xb,
       float* __restrict__ al, float* __restrict__ ar, int N)
{
    __shared__ unsigned short in_lds[64][40];   // bf16 inputs (32 used), pad 8
    __shared__ unsigned short mid[64][72];      // bf16 mid, pad 8

    int tid  = threadIdx.x;
    int lane = tid & 63;
    int w    = tid >> 6;                        // wave 0..3
    int blockStart = blockIdx.x * 64;

    for (int i = tid; i < 64 * 20; i += 256) {
        int node = i / 20, k = i % 20;
        int n = min(blockStart + node, N - 1);
        in_lds[node][k] = f2bf(num_prop[(size_t)n * 20 + k]);
    }
    for (int i = tid; i < 64 * 12; i += 256) {
        int node = i / 12, k = i % 12;
        int n = min(blockStart + node, N - 1);
        in_lds[node][20 + k] = f2bf(cat_prop[(size_t)n * 12 + k]);
    }
    __syncthreads();

    int q   = lane >> 4;
    int c16 = lane & 15;

    bf16x8 ain = *(const bf16x8*)&in_lds[w * 16 + c16][q * 8];
    #pragma unroll
    for (int nt = 0; nt < 4; nt++) {
        bf16x8 b = *(const bf16x8*)&Wb1[nt * 512 + lane * 8];
        f32x4 acc = {0.0f, 0.0f, 0.0f, 0.0f};
        acc = __builtin_amdgcn_mfma_f32_16x16x32_bf16(ain, b, acc, 0, 0, 0);
        int   ch   = nt * 16 + c16;
        float bias = (ch < 32) ? b_num[ch] : b_cat[ch - 32];
        #pragma unroll
        for (int r = 0; r < 4; r++) {
            float s = acc[r] + bias;
            s = LRELU(s);
            mid[w * 16 + q * 4 + r][ch] = f2bf(s);
        }
    }

    bf16x8 a0 = *(const bf16x8*)&mid[w * 16 + c16][q * 8];
    bf16x8 a1 = *(const bf16x8*)&mid[w * 16 + c16][32 + q * 8];

    float pal[4] = {0, 0, 0, 0};
    float par[4] = {0, 0, 0, 0};

    #pragma unroll
    for (int nt = 0; nt < 4; nt++) {
        bf16x8 b0 = *(const bf16x8*)&Wb[(0 * 4 + nt) * 512 + lane * 8];
        bf16x8 b1 = *(const bf16x8*)&Wb[(1 * 4 + nt) * 512 + lane * 8];
        f32x4 acc = {0.0f, 0.0f, 0.0f, 0.0f};
        acc = __builtin_amdgcn_mfma_f32_16x16x32_bf16(a0, b0, acc, 0, 0, 0);
        acc = __builtin_amdgcn_mfma_f32_16x16x32_bf16(a1, b1, acc, 0, 0, 0);

        int   ch  = nt * 16 + c16;
        float bt  = b_tog[ch];
        float atl = att_l[ch];
        float atr = att_r[ch];
        #pragma unroll
        for (int r = 0; r < 4; r++) {
            float s = acc[r] + bt;
            s = LRELU(s);
            int n = blockStart + w * 16 + q * 4 + r;
            if (n < N) xb[(size_t)n * 64 + ch] = f2bf(s);
            pal[r] = fmaf(s, atl, pal[r]);
            par[r] = fmaf(s, atr, par[r]);
        }
    }

    #pragma unroll
    for (int r = 0; r < 4; r++) {
        float pl = pal[r], pr = par[r];
        #pragma unroll
        for (int off = 8; off > 0; off >>= 1) {
            pl += __shfl_xor(pl, off);
            pr += __shfl_xor(pr, off);
        }
        int n = blockStart + w * 16 + q * 4 + r;
        if (c16 == 0 && n < N) { al[n] = pl; ar[n] = pr; }
    }
}

// ---------------------------------------------------------------------------
// K2: radix partition phase 1 (512 threads x 4 edges; no global atomics).
// ---------------------------------------------------------------------------
__global__ void k_bin(const int* __restrict__ src, const int* __restrict__ dst,
                      int* __restrict__ bucket_cnt,
                      int2* __restrict__ buckets, int E, int NB)
{
    __shared__ int  hist[BSIZE];
    __shared__ int  lbase[BSIZE];
    __shared__ int  gbase[BSIZE];
    __shared__ int2 stage[BIN_EPB];

    int tid  = threadIdx.x;          // blockDim = 512
    int base = blockIdx.x * BIN_EPB;

    hist[tid] = 0;
    __syncthreads();

    int s[4], d[4], rk[4];
    #pragma unroll
    for (int k = 0; k < 4; k++) {
        int e = base + k * BSIZE + tid;
        s[k] = -1;
        if (e < E) {
            s[k] = src[e];
            d[k] = dst[e];
            rk[k] = atomicAdd(&hist[d[k] >> BSHIFT], 1);
        }
    }
    __syncthreads();

    int v = hist[tid];
    lbase[tid] = v;
    __syncthreads();
    for (int off = 1; off < BSIZE; off <<= 1) {
        int t = (tid >= off) ? lbase[tid - off] : 0;
        __syncthreads();
        lbase[tid] += t;
        __syncthreads();
    }
    int incl = lbase[tid];
    __syncthreads();
    lbase[tid] = incl - v;
    if (tid < NB && v > 0) gbase[tid] = atomicAdd(&bucket_cnt[tid], v);
    __syncthreads();

    #pragma unroll
    for (int k = 0; k < 4; k++) {
        if (s[k] >= 0) {
            int b = d[k] >> BSHIFT;
            stage[lbase[b] + rk[k]] = make_int2(s[k], d[k]);
        }
    }
    __syncthreads();

    int tot = min(BIN_EPB, E - base);
    for (int i = tid; i < tot; i += BSIZE) {
        int2 p = stage[i];
        int b = p.y >> BSHIFT;
        buckets[(size_t)b * BIN_CAP + gbase[b] + (i - lbase[b])] = p;
    }
}

// ---------------------------------------------------------------------------
// K2b: per-bucket degree histogram + LOCAL exclusive scan of padded lengths
// ((deg+7)&~7) + bucket padded total. Replaces degB + global scan1.
// ---------------------------------------------------------------------------
__global__ void k_degScan(const int2* __restrict__ buckets, const int* __restrict__ bucket_cnt,
                          int* __restrict__ deg, int* __restrict__ row_start,
                          int* __restrict__ bucketTot, int N)
{
    __shared__ int cnt[BSIZE];
    __shared__ int sc[BSIZE];
    int b   = blockIdx.x;
    int tid = threadIdx.x;          // blockDim = 512
    cnt[tid] = 0;
    __syncthreads();

    int ecnt = bucket_cnt[b];
    const int2* bp = buckets + (size_t)b * BIN_CAP;
    for (int i = tid; i < ecnt; i += BSIZE)
        atomicAdd(&cnt[bp[i].y & (BSIZE - 1)], 1);
    __syncthreads();

    int d = cnt[tid];
    int p = (d + 7) & ~7;           // padded row length
    sc[tid] = p;
    __syncthreads();
    for (int off = 1; off < BSIZE; off <<= 1) {
        int t = (tid >= off) ? sc[tid - off] : 0;
        __syncthreads();
        sc[tid] += t;
        __syncthreads();
    }
    int incl = sc[tid];

    int n = b * BSIZE + tid;
    if (n < N) {
        deg[n]       = d;
        row_start[n] = incl - p;    // local (within-bucket) offset
    }
    if (tid == BSIZE - 1) bucketTot[b] = incl;
}

// exclusive scan of NB bucket totals (NB <= 512), one block
__global__ void k_scan2(int* __restrict__ bucketTot, int nb)
{
    __shared__ int sh[BSIZE];
    int tid = threadIdx.x;          // blockDim = 512
    int v = (tid < nb) ? bucketTot[tid] : 0;
    sh[tid] = v;
    __syncthreads();
    for (int off = 1; off < BSIZE; off <<= 1) {
        int t = (tid >= off) ? sh[tid - off] : 0;
        __syncthreads();
        sh[tid] += t;
        __syncthreads();
    }
    if (tid < nb) bucketTot[tid] = sh[tid] - v;     // exclusive
}

// row_start += bucket base; pack ald1 = {al, rsqrt(deg+1)}
__global__ void k_scan3(int* __restrict__ row_start, const int* __restrict__ bucketTot,
                        const int* __restrict__ deg,
                        const float* __restrict__ al, float2* __restrict__ ald1, int N)
{
    int i = blockIdx.x * blockDim.x + threadIdx.x;
    if (i >= N) return;
    row_start[i] += bucketTot[i >> BSHIFT];
    float dv = 1.0f / sqrtf((float)deg[i] + 1.0f);   // +1 self-loop
    ald1[i]  = make_float2(al[i], dv);
}

// ---------------------------------------------------------------------------
// K4: radix partition phase 2: bucket-local CSR fill (LDS cursors) + fused
// layer-1 alpha. 391 blocks now (~1.5/CU vs 196 before — fill2 was
// VALU-issue-bound with 60 CUs idle). Padding alphas pre-memset to 0.
// ---------------------------------------------------------------------------
__global__ void k_fill2(const int2* __restrict__ buckets, const int* __restrict__ bucket_cnt,
                        const int* __restrict__ row_start,
                        const float2* __restrict__ ald, const float* __restrict__ arr,
                        int* __restrict__ srcs, int* __restrict__ dsts,
                        float* __restrict__ alphas)
{
    __shared__ int cur[BSIZE];
    int b   = blockIdx.x;
    int tid = threadIdx.x;          // blockDim = 512
    cur[tid] = 0;
    __syncthreads();

    int cnt = bucket_cnt[b];
    const int2* bp = buckets + (size_t)b * BIN_CAP;
    for (int i = tid; i < cnt; i += BSIZE) {
        int2 p = bp[i];
        int r = p.y & (BSIZE - 1);
        int o = atomicAdd(&cur[r], 1);
        int pos = row_start[p.y] + o;
        float2 as = ald[p.x];           // random 8B (L2/L3)
        float2 ad = ald[p.y];           // bucket-local
        srcs[pos]   = p.x;
        dsts[pos]   = p.y;
        alphas[pos] = fast_tanh(as.x + arr[p.y]) * as.y * ad.y;
    }
}

// ---------------------------------------------------------------------------
// K4b: edge-parallel alpha in CSR order (layer 2 only).
// ---------------------------------------------------------------------------
__global__ void k_alphaE(const int* __restrict__ srcs, const int* __restrict__ dsts,
                         const float2* __restrict__ ald, const float* __restrict__ arr,
                         float* __restrict__ alphas, int P)
{
    int p = blockIdx.x * blockDim.x + threadIdx.x;
    if (p >= P) return;
    int s = srcs[p];
    float a = 0.0f;
    if (s >= 0) {
        int d = dsts[p];
        float2 as = ald[s];
        float2 ad = ald[d];
        a = fast_tanh(as.x + arr[d]) * as.y * ad.y;
    }
    alphas[p] = a;
}

// ---------------------------------------------------------------------------
// K5: gather layer 1 (scalar-offload; r16 structure, near random-line ceiling).
// ---------------------------------------------------------------------------
__global__ void k_gather1(const int* __restrict__ srcs, const float* __restrict__ alphas,
                          const int* __restrict__ row_start, const int* __restrict__ deg,
                          const unsigned short* __restrict__ xb,
                          const float2* __restrict__ ald1, const float* __restrict__ ar,
                          const float* __restrict__ att_l, const float* __restrict__ att_r,
                          unsigned short* __restrict__ h1b, float2* __restrict__ ald2,
                          float* __restrict__ ar2, int N)
{
    int lane = threadIdx.x & 63;
    int n    = __builtin_amdgcn_readfirstlane(blockIdx.x * 4 + (threadIdx.x >> 6));
    if (n >= N) return;

    int    s0   = row_start[n];
    int    cnt  = deg[n];
    int    cntp = (cnt + 7) & ~7;
    float2 self = ald1[n];          // {al[n], dinv[n]}
    float  di   = self.y;
    float  arn  = ar[n];

    float acc = 0.0f;
    for (int j = 0; j < cntp; j += 8) {
        int sv[8]; float av[8], vv[8];
        #pragma unroll
        for (int t = 0; t < 8; t++) {
            sv[t] = max(srcs[s0 + j + t], 0);     // scalar: padding -> row 0
            av[t] = alphas[s0 + j + t];           // scalar: padding -> 0
        }
        #pragma unroll
        for (int t = 0; t < 8; t++) vv[t] = bf2f(xb[(size_t)sv[t] * 64 + lane]);
        #pragma unroll
        for (int t = 0; t < 8; t++) acc = fmaf(vv[t], av[t], acc);
    }

    float selfa = fast_tanh(self.x + arn) * di * di;
    float xnl   = bf2f(xb[(size_t)n * 64 + lane]);
    float v     = acc + (selfa + EPS) * xnl;

    float pl = v * att_l[lane];
    float pr = v * att_r[lane];
    #pragma unroll
    for (int off = 32; off > 0; off >>= 1) {
        pl += __shfl_down(pl, off);
        pr += __shfl_down(pr, off);
    }
    h1b[(size_t)n * 64 + lane] = f2bf(v);
    if (lane == 0) { ald2[n] = make_float2(pl, di); ar2[n] = pr; }
}

// ---------------------------------------------------------------------------
// K6: gather layer 2, fused finalize + abs-smooth.
// ---------------------------------------------------------------------------
__global__ void k_gather2(const int* __restrict__ srcs, const float* __restrict__ alphas,
                          const int* __restrict__ row_start, const int* __restrict__ deg,
                          const unsigned short* __restrict__ h1b,
                          const unsigned short* __restrict__ xb,
                          const float2* __restrict__ ald2, const float* __restrict__ ar2,
                          float* __restrict__ x2, int N)
{
    int lane = threadIdx.x & 63;
    int n    = __builtin_amdgcn_readfirstlane(blockIdx.x * 4 + (threadIdx.x >> 6));
    if (n >= N) return;

    int    s0   = row_start[n];
    int    cnt  = deg[n];
    int    cntp = (cnt + 7) & ~7;
    float2 self = ald2[n];          // {al2[n], dinv[n]}
    float  di   = self.y;
    float  arn  = ar2[n];

    float acc = 0.0f;
    for (int j = 0; j < cntp; j += 8) {
        int sv[8]; float av[8], vv[8];
        #pragma unroll
        for (int t = 0; t < 8; t++) {
            sv[t] = max(srcs[s0 + j + t], 0);
            av[t] = alphas[s0 + j + t];
        }
        #pragma unroll
        for (int t = 0; t < 8; t++) vv[t] = bf2f(h1b[(size_t)sv[t] * 64 + lane]);
        #pragma unroll
        for (int t = 0; t < 8; t++) acc = fmaf(vv[t], av[t], acc);
    }

    float selfa = fast_tanh(self.x + arn) * di * di;
    float h1l   = bf2f(h1b[(size_t)n * 64 + lane]);
    float xnl   = bf2f(xb[(size_t)n * 64 + lane]);
    float v = acc + selfa * h1l + EPS * xnl;
    x2[(size_t)n * 64 + lane] = sqrtf(v * v + 1e-8f);
}

// ---------------------------------------------------------------------------
// K7: per-user CSR segment sum
// ---------------------------------------------------------------------------
__global__ void k_usersum(const float* __restrict__ x2, const int* __restrict__ offs,
                          float* __restrict__ x3, int U)
{
    int u    = blockIdx.x;
    int lane = threadIdx.x;
    if (u >= U) return;
    int s = offs[u], e = offs[u + 1];
    float acc = 0.0f;
    for (int n = s; n < e; n++) acc += x2[(size_t)n * 64 + lane];
    x3[(size_t)u * 64 + lane] = acc;
}

// ---------------------------------------------------------------------------
// K8: head
// ---------------------------------------------------------------------------
__global__ void k_head(const float* __restrict__ x3, const int* __restrict__ re_index,
                       const float* __restrict__ W_f1, const float* __restrict__ b_f1,
                       const float* __restrict__ W_lab, const float* __restrict__ b_lab,
                       float* __restrict__ out, int U)
{
    int u = blockIdx.x * blockDim.x + threadIdx.x;
    if (u >= U) return;
    int r = re_index[u];
    const float* y = x3 + (size_t)r * 64;
    float yv[64];
    #pragma unroll
    for (int k = 0; k < 64; k++) yv[k] = y[k];
    float o0 = b_lab[0], o1 = b_lab[1];
    for (int j = 0; j < 32; j++) {
        float s = b_f1[j];
        #pragma unroll 8
        for (int k = 0; k < 64; k++) s = fmaf(yv[k], W_f1[k * 32 + j], s);
        s = LRELU(s);
        o0 = fmaf(s, W_lab[j * 2 + 0], o0);
        o1 = fmaf(s, W_lab[j * 2 + 1], o1);
    }
    out[(size_t)u * 2 + 0] = o0;
    out[(size_t)u * 2 + 1] = o1;
}

// ---------------------------------------------------------------------------
extern "C" void kernel_launch(void* const* d_in, const int* in_sizes, int n_in,
                              void* d_out, int out_size, void* d_ws, size_t ws_size,
                              hipStream_t stream)
{
    const float* num_prop = (const float*)d_in[0];
    const float* cat_prop = (const float*)d_in[1];
    const int*   offs     = (const int*)d_in[2];
    const int*   edge     = (const int*)d_in[3];
    const int*   re_index = (const int*)d_in[4];
    const float* W_num    = (const float*)d_in[5];
    const float* b_num    = (const float*)d_in[6];
    const float* W_cat    = (const float*)d_in[7];
    const float* b_cat    = (const float*)d_in[8];
    const float* W_tog    = (const float*)d_in[9];
    const float* b_tog    = (const float*)d_in[10];
    const float* att_l    = (const float*)d_in[11];
    const float* att_r    = (const float*)d_in[12];
    const float* W_f1     = (const float*)d_in[13];
    const float* b_f1     = (const float*)d_in[14];
    const float* W_lab    = (const float*)d_in[15];
    const float* b_lab    = (const float*)d_in[16];

    const int N = in_sizes[0] / 20;
    const int E = in_sizes[3] / 2;
    const int U = in_sizes[4];

    const int* src = edge;       // edge_index[0]
    const int* dst = edge + E;   // edge_index[1]

    const int    NB      = (N + BSIZE - 1) >> BSHIFT;          // dst buckets
    const size_t srcsCap = (size_t)E + 7ull * (size_t)N + 64;  // padded CSR capacity

    // workspace carve-up (4-byte units; int2/float2 8B-aligned by layout)
    float* ws = (float*)d_ws;
    size_t off = 0;
    unsigned short* xb  = (unsigned short*)(ws + off); off += (size_t)N * 32;  // bf16 x
    unsigned short* h1b = (unsigned short*)(ws + off); off += (size_t)N * 32;  // bf16 h1
    float*  B    = ws + off; off += (size_t)N * 64;   // x2 (fp32)
    float2* ald1 = (float2*)(ws + off); off += (size_t)N * 2;
    float2* ald2 = (float2*)(ws + off); off += (size_t)N * 2;
    int2*   buckets = (int2*)(ws + off); off += (size_t)NB * BIN_CAP * 2;
    float*  al   = ws + off; off += N;
    float*  ar   = ws + off; off += N;
    float*  ar2  = ws + off; off += N;
    float*  x3   = ws + off; off += (size_t)U * 64;
    unsigned short* Wb  = (unsigned short*)(ws + off); off += 2048;  // 4096 bf16
    unsigned short* Wb1 = (unsigned short*)(ws + off); off += 1024;  // 2048 bf16
    int*    deg        = (int*)(ws + off); off += N;
    int*    row_start  = (int*)(ws + off); off += N;
    int*    bucket_cnt = (int*)(ws + off); off += NB;
    int*    bucketTot  = (int*)(ws + off); off += BSIZE;
    int*    srcs       = (int*)(ws + off); off += srcsCap;
    int*    dsts       = (int*)(ws + off); off += srcsCap;
    float*  alphas     = (float*)(ws + off); off += srcsCap;

    hipMemsetAsync(bucket_cnt, 0, (size_t)NB * 4, stream);
    hipMemsetAsync(srcs, 0xFF, srcsCap * 4, stream);   // padding slots = -1
    hipMemsetAsync(alphas, 0, srcsCap * 4, stream);    // padding alphas = 0

    const int nbN4  = (N + 3) / 4;          // wave-per-node gather kernels
    const int nbBin = (E + BIN_EPB - 1) / BIN_EPB;
    const int nbCap = (int)((srcsCap + 255) / 256);

    // pack both weight matrices into MFMA B-fragment bf16 layout
    k_prep<<<1, 256, 0, stream>>>(W_num, W_cat, W_tog, Wb, Wb1);

    // all-MFMA feature MLP: block = 64 nodes
    k_feat<<<(N + 63) / 64, 256, 0, stream>>>(num_prop, cat_prop, Wb1, b_num, b_cat,
                                              Wb, b_tog, att_l, att_r, xb, al, ar, N);

    // radix partition phase 1 (no global atomics)
    k_bin<<<nbBin, BSIZE, 0, stream>>>(src, dst, bucket_cnt, buckets, E, NB);

    // per-bucket degree histogram + local padded scan (replaces degB + scan1)
    k_degScan<<<NB, BSIZE, 0, stream>>>(buckets, bucket_cnt, deg, row_start, bucketTot, N);
    k_scan2<<<1, BSIZE, 0, stream>>>(bucketTot, NB);
    k_scan3<<<(N + 255) / 256, 256, 0, stream>>>(row_start, bucketTot, deg, al, ald1, N);

    // radix partition phase 2: bucket-local CSR fill + fused layer-1 alpha
    k_fill2<<<NB, BSIZE, 0, stream>>>(buckets, bucket_cnt, row_start, ald1, ar,
                                      srcs, dsts, alphas);

    // ---- FAConv layer 1 (h = h0 = x): scalar-offload gather ----
    k_gather1<<<nbN4, 256, 0, stream>>>(srcs, alphas, row_start, deg, xb, ald1, ar,
                                        att_l, att_r, h1b, ald2, ar2, N);

    // ---- FAConv layer 2 (h = h1, h0 = x) ----
    k_alphaE<<<nbCap, 256, 0, stream>>>(srcs, dsts, ald2, ar2, alphas, (int)srcsCap);
    k_gather2<<<nbN4, 256, 0, stream>>>(srcs, alphas, row_start, deg, h1b, xb,
                                        ald2, ar2, B, N);

    // ---- per-user pooling + head ----
    k_usersum<<<U, 64, 0, stream>>>(B, offs, x3, U);
    k_head<<<(U + 255) / 256, 256, 0, stream>>>(x3, re_index, W_f1, b_f1, W_lab, b_lab,
                                                (float*)d_out, U);
}